// Round 1
// baseline (1537.584 us; speedup 1.0000x reference)
//
#include <hip/hip_runtime.h>

#define Tt 4096
#define Bb 2
#define Ss 2048
#define Dd 1024
#define Hh 16
#define KVHn 4
#define HDn 64
#define En 8
#define TOPKn 2
#define Fn 4096

#define BM 128
#define BN 128
#define BK 32
#define LP 40   // LDS row stride (elems) for 128B-row bank spread, 16B aligned

typedef __attribute__((ext_vector_type(4))) float f32x4;
typedef __attribute__((ext_vector_type(8))) short bfrag;
typedef __attribute__((ext_vector_type(4))) short s16x4;

__device__ __forceinline__ unsigned short f2bf(float f) {
    unsigned u = __builtin_bit_cast(unsigned, f);
    u = (u + 0x7fffu + ((u >> 16) & 1u)) >> 16;
    return (unsigned short)u;
}
__device__ __forceinline__ float bf2f(unsigned short b) {
    unsigned u = ((unsigned)b) << 16;
    return __builtin_bit_cast(float, u);
}
// split f32 -> hi bf16 + lo bf16 (residual), for 3-pass "bf16x3" f32-fidelity MFMA
__device__ __forceinline__ void split8a(const float* va, bfrag* ph, bfrag* pl) {
    bfrag th, tl;
#pragma unroll
    for (int j = 0; j < 8; j++) {
        unsigned short hu = f2bf(va[j]);
        th[j] = (short)hu;
        tl[j] = (short)f2bf(va[j] - bf2f(hu));
    }
    *ph = th; *pl = tl;
}

// ---------------- RMSNorm: one block per row, D=1024, 256 thr x 4 ----------------
__global__ __launch_bounds__(256)
void rmsnorm_k(const float* __restrict__ x, const float* __restrict__ w,
               float* __restrict__ out)
{
    const int row = blockIdx.x;
    const int tid = threadIdx.x;
    const int lane = tid & 63, wid = tid >> 6;
    const float* xr = x + (size_t)row * Dd;
    f32x4 t4 = *(const f32x4*)(xr + tid * 4);
    float s = t4.x*t4.x + t4.y*t4.y + t4.z*t4.z + t4.w*t4.w;
#pragma unroll
    for (int o = 1; o < 64; o <<= 1) s += __shfl_xor(s, o, 64);
    __shared__ float red[4];
    if (lane == 0) red[wid] = s;
    __syncthreads();
    float tot = red[0] + red[1] + red[2] + red[3];
    float inv = rsqrtf(tot * (1.0f / Dd) + 1e-6f);
    f32x4 w4 = *(const f32x4*)(w + tid * 4);
    f32x4 o4;
    o4.x = t4.x * inv * w4.x;
    o4.y = t4.y * inv * w4.y;
    o4.z = t4.z * inv * w4.z;
    o4.w = t4.w * inv * w4.w;
    *(f32x4*)(out + (size_t)row * Dd + tid * 4) = o4;
}

// ---------------- RoPE tables in f64 (pos up to 2047: f32 angle rounding is 1e-4-class) ----
__global__ __launch_bounds__(256)
void rope_tab_k(float* __restrict__ ct, float* __restrict__ st)
{
    int idx = blockIdx.x * 256 + threadIdx.x;
    if (idx < Ss * 32) {
        int s = idx >> 5, i = idx & 31;
        double inv = pow(10000.0, -((double)(2 * i)) / 64.0);
        double a = (double)s * inv;
        double sn, cs;
        sincos(a, &sn, &cs);
        ct[idx] = (float)cs;
        st[idx] = (float)sn;
    }
}

// ---------------- RoPE (HF rotate-half), in-place on q_pre/k_pre ----------------
__global__ __launch_bounds__(256)
void rope_k(float* __restrict__ q, float* __restrict__ k,
            const float* __restrict__ ct, const float* __restrict__ st)
{
    int idx = blockIdx.x * 256 + threadIdx.x;
    const int nq = Tt * Hh * 32;
    if (idx < nq) {
        int i = idx & 31, hh = (idx >> 5) & (Hh - 1), t = idx >> 9;
        int s = t & (Ss - 1);
        float cs = ct[s * 32 + i], sn = st[s * 32 + i];
        float* base = q + (size_t)t * (Hh * HDn) + hh * HDn + i;
        float x1 = base[0], x2 = base[32];
        base[0]  = x1 * cs - x2 * sn;
        base[32] = x2 * cs + x1 * sn;
    } else {
        int j = idx - nq;
        if (j < Tt * KVHn * 32) {
            int i = j & 31, hh = (j >> 5) & (KVHn - 1), t = j >> 7;
            int s = t & (Ss - 1);
            float cs = ct[s * 32 + i], sn = st[s * 32 + i];
            float* base = k + (size_t)t * (KVHn * HDn) + hh * HDn + i;
            float x1 = base[0], x2 = base[32];
            base[0]  = x1 * cs - x2 * sn;
            base[32] = x2 * cs + x1 * sn;
        }
    }
}

// ---------------- GEMM workhorse ----------------
// MODE 0: C=A@B (f32 out)                 [split bf16x3: f32 fidelity]
// MODE 1: C=resid+A@B (f32 out)           [split]
// MODE 2: gathered A rows -> act bf16     [plain bf16]
// MODE 3: gathered A rows; act=silu(act)*acc*gw  [plain]
// MODE 4: A=act bf16; atomicAdd into C rows=tok  [plain]
template<int MODE>
__global__ __launch_bounds__(256)
void gemm_k(const float* __restrict__ Af, const unsigned short* __restrict__ Abf,
            const float* __restrict__ Bf,
            float* __restrict__ Cf, unsigned short* __restrict__ Cbf,
            const float* __restrict__ resid,
            const int* __restrict__ toklist, const float* __restrict__ gwlist,
            const int* __restrict__ counts, const int* __restrict__ offsets,
            const int M, const int N, const int K, const int ntiles)
{
    constexpr bool SPLIT = (MODE <= 1);
    const int bid = blockIdx.x;
    const int nt = bid % ntiles, mt = bid / ntiles;
    const int e = blockIdx.y;
    int Meff = M;
    const int* tok = nullptr;
    const float* gw = nullptr;
    int rowoff = 0;
    const float* Bp = Bf;
    if (MODE >= 2) {
        Meff = counts[e];
        if (mt * BM >= Meff) return;
        tok = toklist + e * Tt;
        gw = gwlist + e * Tt;
        rowoff = offsets[e];
        Bp = Bf + (size_t)e * K * N;
    }
    __shared__ __align__(16) unsigned short Ahi[BM * LP];
    __shared__ __align__(16) unsigned short Bhi[BN * LP];
    __shared__ __align__(16) unsigned short Alo[SPLIT ? BM * LP : 1];
    __shared__ __align__(16) unsigned short Blo[SPLIT ? BN * LP : 1];

    const int tid = threadIdx.x;
    const int lane = tid & 63, wid = tid >> 6;
    const int wrow = (wid >> 1) * 64, wcol = (wid & 1) * 64;
    const int l15 = lane & 15, lhi = lane >> 4;
    const int row0 = mt * BM, col0 = nt * BN;

    f32x4 acc[4][4];
#pragma unroll
    for (int i = 0; i < 4; i++)
#pragma unroll
        for (int j = 0; j < 4; j++) { acc[i][j].x = 0.f; acc[i][j].y = 0.f; acc[i][j].z = 0.f; acc[i][j].w = 0.f; }

    for (int k0 = 0; k0 < K; k0 += BK) {
        // ---- stage A tile [BM x BK] ----
#pragma unroll
        for (int it = 0; it < 4; it++) {
            int idx = tid + it * 256;
            int m = idx >> 3, kc = (idx & 7) << 2;
            int pr = row0 + m;
            if (MODE == 4) {
                s16x4 a4; a4[0] = 0; a4[1] = 0; a4[2] = 0; a4[3] = 0;
                if (pr < Meff) a4 = *(const s16x4*)(Abf + (size_t)(rowoff + pr) * K + k0 + kc);
                *(s16x4*)&Ahi[m * LP + kc] = a4;
            } else {
                f32x4 t4; t4.x = 0.f; t4.y = 0.f; t4.z = 0.f; t4.w = 0.f;
                if (MODE <= 1) {
                    t4 = *(const f32x4*)(Af + (size_t)pr * K + k0 + kc);   // M multiple of BM
                } else {
                    if (pr < Meff) t4 = *(const f32x4*)(Af + (size_t)tok[pr] * K + k0 + kc);
                }
                unsigned short u0 = f2bf(t4.x), u1 = f2bf(t4.y), u2 = f2bf(t4.z), u3 = f2bf(t4.w);
                s16x4 hi; hi[0] = (short)u0; hi[1] = (short)u1; hi[2] = (short)u2; hi[3] = (short)u3;
                *(s16x4*)&Ahi[m * LP + kc] = hi;
                if constexpr (SPLIT) {
                    s16x4 lo;
                    lo[0] = (short)f2bf(t4.x - bf2f(u0));
                    lo[1] = (short)f2bf(t4.y - bf2f(u1));
                    lo[2] = (short)f2bf(t4.z - bf2f(u2));
                    lo[3] = (short)f2bf(t4.w - bf2f(u3));
                    *(s16x4*)&Alo[m * LP + kc] = lo;
                }
            }
        }
        // ---- stage B tile transposed: Bsl[n][k] ----
#pragma unroll
        for (int it = 0; it < 4; it++) {
            int idx = tid + it * 256;
            int n = idx & (BN - 1), kc = (idx >> 7) << 2;
            const float* bp = Bp + (size_t)(k0 + kc) * N + col0 + n;
            float v0 = bp[0], v1 = bp[N], v2 = bp[2 * (size_t)N], v3 = bp[3 * (size_t)N];
            unsigned short u0 = f2bf(v0), u1 = f2bf(v1), u2 = f2bf(v2), u3 = f2bf(v3);
            s16x4 hi; hi[0] = (short)u0; hi[1] = (short)u1; hi[2] = (short)u2; hi[3] = (short)u3;
            *(s16x4*)&Bhi[n * LP + kc] = hi;
            if constexpr (SPLIT) {
                s16x4 lo;
                lo[0] = (short)f2bf(v0 - bf2f(u0));
                lo[1] = (short)f2bf(v1 - bf2f(u1));
                lo[2] = (short)f2bf(v2 - bf2f(u2));
                lo[3] = (short)f2bf(v3 - bf2f(u3));
                *(s16x4*)&Blo[n * LP + kc] = lo;
            }
        }
        __syncthreads();
        bfrag ah[4], bh[4], al[4], bl[4];
#pragma unroll
        for (int mi = 0; mi < 4; mi++) {
            int rb = (wrow + mi * 16 + l15) * LP + lhi * 8;
            ah[mi] = *(const bfrag*)&Ahi[rb];
            if constexpr (SPLIT) al[mi] = *(const bfrag*)&Alo[rb];
        }
#pragma unroll
        for (int ni = 0; ni < 4; ni++) {
            int rb = (wcol + ni * 16 + l15) * LP + lhi * 8;
            bh[ni] = *(const bfrag*)&Bhi[rb];
            if constexpr (SPLIT) bl[ni] = *(const bfrag*)&Blo[rb];
        }
#pragma unroll
        for (int mi = 0; mi < 4; mi++)
#pragma unroll
            for (int ni = 0; ni < 4; ni++) {
                acc[mi][ni] = __builtin_amdgcn_mfma_f32_16x16x32_bf16(ah[mi], bh[ni], acc[mi][ni], 0, 0, 0);
                if constexpr (SPLIT) {
                    acc[mi][ni] = __builtin_amdgcn_mfma_f32_16x16x32_bf16(ah[mi], bl[ni], acc[mi][ni], 0, 0, 0);
                    acc[mi][ni] = __builtin_amdgcn_mfma_f32_16x16x32_bf16(al[mi], bh[ni], acc[mi][ni], 0, 0, 0);
                }
            }
        __syncthreads();
    }
    // ---- epilogue: C/D frag row = (lane>>4)*4 + t, col = lane&15 ----
#pragma unroll
    for (int mi = 0; mi < 4; mi++) {
#pragma unroll
        for (int t = 0; t < 4; t++) {
            int r = wrow + mi * 16 + lhi * 4 + t;
            int pr = row0 + r;
            if (MODE <= 1) {
                if (pr < M) {
#pragma unroll
                    for (int ni = 0; ni < 4; ni++) {
                        int gc = col0 + wcol + ni * 16 + l15;
                        float vv = acc[mi][ni][t];
                        if (MODE == 1) vv += resid[(size_t)pr * N + gc];
                        Cf[(size_t)pr * N + gc] = vv;
                    }
                }
            } else if (MODE == 2) {
                if (pr < Meff) {
#pragma unroll
                    for (int ni = 0; ni < 4; ni++) {
                        int gc = col0 + wcol + ni * 16 + l15;
                        Cbf[(size_t)(rowoff + pr) * N + gc] = f2bf(acc[mi][ni][t]);
                    }
                }
            } else if (MODE == 3) {
                if (pr < Meff) {
                    float gwv = gw[pr];
#pragma unroll
                    for (int ni = 0; ni < 4; ni++) {
                        int gc = col0 + wcol + ni * 16 + l15;
                        size_t ix = (size_t)(rowoff + pr) * N + gc;
                        float g = bf2f(Cbf[ix]);
                        float sg = g / (1.0f + expf(-g));   // silu
                        Cbf[ix] = f2bf(sg * acc[mi][ni][t] * gwv);
                    }
                }
            } else {
                if (pr < Meff) {
                    int trow = tok[pr];
#pragma unroll
                    for (int ni = 0; ni < 4; ni++) {
                        int gc = col0 + wcol + ni * 16 + l15;
                        atomicAdd(&Cf[(size_t)trow * N + gc], acc[mi][ni][t]);
                    }
                }
            }
        }
    }
}

// ---------------- Flash attention (causal, GQA), split-bf16 for f32 fidelity ----------
// grid: (S/64, H, B); 4 waves, each owns 16 q rows.
__global__ __launch_bounds__(256)
void attn_k(const float* __restrict__ q, const float* __restrict__ kk,
            const float* __restrict__ vv, float* __restrict__ ctx)
{
    const int qt = blockIdx.x, h = blockIdx.y, b = blockIdx.z;
    const int kvh = h >> 2;   // H/KVH = 4
    const int tid = threadIdx.x;
    const int lane = tid & 63, wid = tid >> 6;
    const int l15 = lane & 15, lhi = lane >> 4;

    __shared__ __align__(16) unsigned short Khi[64 * 64];
    __shared__ __align__(16) unsigned short Klo[64 * 64];
    __shared__ __align__(16) unsigned short Vhi[64 * 72];   // V^T: [d][kv], pad 8
    __shared__ __align__(16) unsigned short Vlo[64 * 72];
    __shared__ __align__(16) unsigned short Phi[4 * 16 * 72];
    __shared__ __align__(16) unsigned short Plo[4 * 16 * 72];

    // Q fragments (A rows = l15), scale 1/8 folded in (exact pow2)
    bfrag qh[2], ql[2];
    {
        const int qrow = qt * 64 + wid * 16 + l15;
        const float* qb = q + ((size_t)(b * Ss) + qrow) * (Hh * HDn) + h * HDn;
#pragma unroll
        for (int ks = 0; ks < 2; ks++) {
            const float* p = qb + ks * 32 + lhi * 8;
            f32x4 u0 = *(const f32x4*)p;
            f32x4 u1 = *(const f32x4*)(p + 4);
            float va[8] = { u0.x * 0.125f, u0.y * 0.125f, u0.z * 0.125f, u0.w * 0.125f,
                            u1.x * 0.125f, u1.y * 0.125f, u1.z * 0.125f, u1.w * 0.125f };
            split8a(va, &qh[ks], &ql[ks]);
        }
    }
    f32x4 O[4];
#pragma unroll
    for (int ni = 0; ni < 4; ni++) { O[ni].x = 0.f; O[ni].y = 0.f; O[ni].z = 0.f; O[ni].w = 0.f; }
    float m_r[4] = { -1e30f, -1e30f, -1e30f, -1e30f };
    float l_r[4] = { 0.f, 0.f, 0.f, 0.f };

    for (int kt = 0; kt <= qt; kt++) {
        // ---- stage K tile [64 kv][64 d], rows 128B, XOR-swizzled 16B units ----
#pragma unroll
        for (int it = 0; it < 2; it++) {
            int ci = tid + it * 256;
            int kv = ci >> 3, d0 = (ci & 7) << 3;
            const float* p = kk + ((size_t)(b * Ss) + (size_t)kt * 64 + kv) * (KVHn * HDn) + kvh * HDn + d0;
            f32x4 u0 = *(const f32x4*)p;
            f32x4 u1 = *(const f32x4*)(p + 4);
            float va[8] = { u0.x, u0.y, u0.z, u0.w, u1.x, u1.y, u1.z, u1.w };
            bfrag th, tl;
            split8a(va, &th, &tl);
            int boff = kv * 128 + ((d0 * 2) ^ ((kv & 7) << 4));
            *(bfrag*)((char*)Khi + boff) = th;
            *(bfrag*)((char*)Klo + boff) = tl;
        }
        // ---- stage V transposed: V^T[d][kv] ----
#pragma unroll
        for (int it = 0; it < 2; it++) {
            int ci = tid + it * 256;
            int d = ci >> 3, kv0 = (ci & 7) << 3;
            float va[8];
#pragma unroll
            for (int j = 0; j < 8; j++)
                va[j] = vv[((size_t)(b * Ss) + (size_t)kt * 64 + kv0 + j) * (KVHn * HDn) + kvh * HDn + d];
            bfrag th, tl;
            split8a(va, &th, &tl);
            *(bfrag*)&Vhi[d * 72 + kv0] = th;
            *(bfrag*)&Vlo[d * 72 + kv0] = tl;
        }
        __syncthreads();
        // ---- S = Q K^T (3-pass split) ----
        f32x4 sf[4];
#pragma unroll
        for (int ni = 0; ni < 4; ni++) { sf[ni].x = 0.f; sf[ni].y = 0.f; sf[ni].z = 0.f; sf[ni].w = 0.f; }
#pragma unroll
        for (int ks = 0; ks < 2; ks++) {
#pragma unroll
            for (int ni = 0; ni < 4; ni++) {
                int kv = ni * 16 + l15;
                int dof = ks * 64 + lhi * 16;
                int boff = kv * 128 + (dof ^ ((kv & 7) << 4));
                bfrag kfh = *(const bfrag*)((const char*)Khi + boff);
                bfrag kfl = *(const bfrag*)((const char*)Klo + boff);
                sf[ni] = __builtin_amdgcn_mfma_f32_16x16x32_bf16(qh[ks], kfh, sf[ni], 0, 0, 0);
                sf[ni] = __builtin_amdgcn_mfma_f32_16x16x32_bf16(qh[ks], kfl, sf[ni], 0, 0, 0);
                sf[ni] = __builtin_amdgcn_mfma_f32_16x16x32_bf16(ql[ks], kfh, sf[ni], 0, 0, 0);
            }
        }
        // ---- causal mask on diagonal tile ----
        if (kt == qt) {
#pragma unroll
            for (int ni = 0; ni < 4; ni++)
#pragma unroll
                for (int t = 0; t < 4; t++)
                    if (ni * 16 + l15 > wid * 16 + lhi * 4 + t) sf[ni][t] = -1e30f;
        }
        // ---- online softmax (rows r = lhi*4+t; reduce over 16 lanes of group) ----
        float sfac[4];
#pragma unroll
        for (int t = 0; t < 4; t++) {
            float mx = fmaxf(fmaxf(sf[0][t], sf[1][t]), fmaxf(sf[2][t], sf[3][t]));
#pragma unroll
            for (int o = 1; o < 16; o <<= 1) mx = fmaxf(mx, __shfl_xor(mx, o, 64));
            float mn = fmaxf(m_r[t], mx);
            float sc = expf(m_r[t] - mn);
            m_r[t] = mn;
            float rs = 0.f;
#pragma unroll
            for (int ni = 0; ni < 4; ni++) {
                float p = expf(sf[ni][t] - mn);
                sf[ni][t] = p;
                rs += p;
            }
#pragma unroll
            for (int o = 1; o < 16; o <<= 1) rs += __shfl_xor(rs, o, 64);
            l_r[t] = l_r[t] * sc + rs;
            sfac[t] = sc;
        }
#pragma unroll
        for (int ni = 0; ni < 4; ni++)
#pragma unroll
            for (int t = 0; t < 4; t++) O[ni][t] *= sfac[t];
        // ---- write P (split) to per-wave LDS ----
#pragma unroll
        for (int ni = 0; ni < 4; ni++)
#pragma unroll
            for (int t = 0; t < 4; t++) {
                float p = sf[ni][t];
                unsigned short hu = f2bf(p);
                int ix = (wid * 16 + lhi * 4 + t) * 72 + ni * 16 + l15;
                Phi[ix] = hu;
                Plo[ix] = f2bf(p - bf2f(hu));
            }
        __syncthreads();
        // ---- O += P V (3-pass split) ----
#pragma unroll
        for (int ks = 0; ks < 2; ks++) {
            int pb = (wid * 16 + l15) * 72 + ks * 32 + lhi * 8;
            bfrag pfh = *(const bfrag*)&Phi[pb];
            bfrag pfl = *(const bfrag*)&Plo[pb];
#pragma unroll
            for (int ni = 0; ni < 4; ni++) {
                int vb = (ni * 16 + l15) * 72 + ks * 32 + lhi * 8;
                bfrag vfh = *(const bfrag*)&Vhi[vb];
                bfrag vfl = *(const bfrag*)&Vlo[vb];
                O[ni] = __builtin_amdgcn_mfma_f32_16x16x32_bf16(pfh, vfh, O[ni], 0, 0, 0);
                O[ni] = __builtin_amdgcn_mfma_f32_16x16x32_bf16(pfh, vfl, O[ni], 0, 0, 0);
                O[ni] = __builtin_amdgcn_mfma_f32_16x16x32_bf16(pfl, vfh, O[ni], 0, 0, 0);
            }
        }
        __syncthreads();
    }
    // ---- normalize + store ctx f32 ----
#pragma unroll
    for (int t = 0; t < 4; t++) {
        float inv = 1.0f / l_r[t];
        int qrow = qt * 64 + wid * 16 + lhi * 4 + t;
        float* cb = ctx + ((size_t)(b * Ss) + qrow) * (Hh * HDn) + h * HDn;
#pragma unroll
        for (int ni = 0; ni < 4; ni++)
            cb[ni * 16 + l15] = O[ni][t] * inv;
    }
}

// ---------------- Router: f32 logits/softmax/top2; build per-expert lists ----------------
__global__ __launch_bounds__(256)
void router_k(const float* __restrict__ h2, const float* __restrict__ rw,
              float* __restrict__ probs, int* __restrict__ counts,
              int* __restrict__ toklist, float* __restrict__ gwlist)
{
    const int t = blockIdx.x;
    const int tid = threadIdx.x;
    const int lane = tid & 63, wid = tid >> 6;
    f32x4 x4 = *(const f32x4*)(h2 + (size_t)t * Dd + tid * 4);
    float part[En];
#pragma unroll
    for (int e = 0; e < En; e++) {
        f32x4 w4 = *(const f32x4*)(rw + (size_t)e * Dd + tid * 4);
        part[e] = x4.x * w4.x + x4.y * w4.y + x4.z * w4.z + x4.w * w4.w;
    }
#pragma unroll
    for (int e = 0; e < En; e++)
#pragma unroll
        for (int o = 1; o < 64; o <<= 1) part[e] += __shfl_xor(part[e], o, 64);
    __shared__ float red[4][En];
    if (lane == 0) {
#pragma unroll
        for (int e = 0; e < En; e++) red[wid][e] = part[e];
    }
    __syncthreads();
    if (tid == 0) {
        float lg[En];
        float mx = -1e30f;
#pragma unroll
        for (int e = 0; e < En; e++) {
            lg[e] = red[0][e] + red[1][e] + red[2][e] + red[3][e];
            mx = fmaxf(mx, lg[e]);
        }
        float pe[En], ssum = 0.f;
#pragma unroll
        for (int e = 0; e < En; e++) { pe[e] = expf(lg[e] - mx); ssum += pe[e]; }
        float inv = 1.0f / ssum;
#pragma unroll
        for (int e = 0; e < En; e++) { pe[e] *= inv; probs[(size_t)t * En + e] = pe[e]; }
        // top2, lowest index wins ties (matches stable top_k)
        int i0 = 0;
#pragma unroll
        for (int e = 1; e < En; e++) if (pe[e] > pe[i0]) i0 = e;
        int i1 = (i0 == 0) ? 1 : 0;
#pragma unroll
        for (int e = 0; e < En; e++) if (e != i0 && pe[e] > pe[i1]) i1 = e;
        float s2 = pe[i0] + pe[i1];
        int s0 = atomicAdd(&counts[i0], 1);
        toklist[i0 * Tt + s0] = t; gwlist[i0 * Tt + s0] = pe[i0] / s2;
        int s1 = atomicAdd(&counts[i1], 1);
        toklist[i1 * Tt + s1] = t; gwlist[i1 * Tt + s1] = pe[i1] / s2;
    }
}

// ---------------- Finalize: expert offsets + balance loss (deterministic reduce) ----------
__global__ __launch_bounds__(256)
void finalize_k(const float* __restrict__ probs, const int* __restrict__ counts,
                int* __restrict__ offsets, float* __restrict__ loss_out)
{
    const int tid = threadIdx.x, lane = tid & 63, wid = tid >> 6;
    float ps[En];
#pragma unroll
    for (int e = 0; e < En; e++) ps[e] = 0.f;
    for (int t = tid; t < Tt; t += 256) {
#pragma unroll
        for (int e = 0; e < En; e++) ps[e] += probs[(size_t)t * En + e];
    }
#pragma unroll
    for (int e = 0; e < En; e++)
#pragma unroll
        for (int o = 1; o < 64; o <<= 1) ps[e] += __shfl_xor(ps[e], o, 64);
    __shared__ float red[4][En];
    if (lane == 0) {
#pragma unroll
        for (int e = 0; e < En; e++) red[wid][e] = ps[e];
    }
    __syncthreads();
    if (tid == 0) {
        int o = 0;
        float bl = 0.f;
#pragma unroll
        for (int e = 0; e < En; e++) {
            offsets[e] = o; o += counts[e];
            float pm = (red[0][e] + red[1][e] + red[2][e] + red[3][e]) * (1.0f / Tt);
            float fr = (float)counts[e] * (1.0f / (Tt * TOPKn));
            bl += fr * pm;
        }
        loss_out[0] = 0.01f * (float)En * bl;
    }
}

extern "C" void kernel_launch(void* const* d_in, const int* in_sizes, int n_in,
                              void* d_out, int out_size, void* d_ws, size_t ws_size,
                              hipStream_t stream)
{
    (void)in_sizes; (void)n_in; (void)out_size; (void)ws_size;
    const float* hs  = (const float*)d_in[0];
    const float* ln1 = (const float*)d_in[1];
    const float* wq  = (const float*)d_in[2];
    const float* wk  = (const float*)d_in[3];
    const float* wv  = (const float*)d_in[4];
    const float* wo  = (const float*)d_in[5];
    const float* ln2 = (const float*)d_in[6];
    const float* rw  = (const float*)d_in[7];
    const float* wg  = (const float*)d_in[8];
    const float* wu  = (const float*)d_in[9];
    const float* wd  = (const float*)d_in[10];
    float* out = (float*)d_out;

    char* ws = (char*)d_ws;
    size_t off = 0;
    auto nxt = [&](size_t bytes) { char* p = ws + off; off += (bytes + 255) & ~(size_t)255; return p; };
    float* h1    = (float*)nxt((size_t)Tt * Dd * 4);
    float* qp    = (float*)nxt((size_t)Tt * Hh * HDn * 4);
    float* kp    = (float*)nxt((size_t)Tt * KVHn * HDn * 4);
    float* vp    = (float*)nxt((size_t)Tt * KVHn * HDn * 4);
    float* ctx   = (float*)nxt((size_t)Tt * Hh * HDn * 4);
    float* h2    = (float*)nxt((size_t)Tt * Dd * 4);
    unsigned short* act = (unsigned short*)nxt((size_t)2 * Tt * Fn * 2);
    float* probs = (float*)nxt((size_t)Tt * En * 4);
    int*   tokl  = (int*)nxt((size_t)En * Tt * 4);
    float* gwl   = (float*)nxt((size_t)En * Tt * 4);
    float* ctab  = (float*)nxt((size_t)Ss * 32 * 4);
    float* stab  = (float*)nxt((size_t)Ss * 32 * 4);
    int*   counts = (int*)nxt(256);
    int*   offs   = (int*)nxt(256);

    rope_tab_k<<<dim3(Ss * 32 / 256), 256, 0, stream>>>(ctab, stab);
    rmsnorm_k<<<dim3(Tt), 256, 0, stream>>>(hs, ln1, h1);
    // QKV projections (split bf16x3, f32 out)
    gemm_k<0><<<dim3(32 * 8), 256, 0, stream>>>(h1, nullptr, wq, qp, nullptr, nullptr,
                                                nullptr, nullptr, nullptr, nullptr, Tt, 1024, 1024, 8);
    gemm_k<0><<<dim3(32 * 2), 256, 0, stream>>>(h1, nullptr, wk, kp, nullptr, nullptr,
                                                nullptr, nullptr, nullptr, nullptr, Tt, 256, 1024, 2);
    gemm_k<0><<<dim3(32 * 2), 256, 0, stream>>>(h1, nullptr, wv, vp, nullptr, nullptr,
                                                nullptr, nullptr, nullptr, nullptr, Tt, 256, 1024, 2);
    rope_k<<<dim3((Tt * Hh * 32 + Tt * KVHn * 32) / 256), 256, 0, stream>>>(qp, kp, ctab, stab);
    attn_k<<<dim3(Ss / 64, Hh, Bb), 256, 0, stream>>>(qp, kp, vp, ctx);
    // out = hidden + ctx @ wo
    gemm_k<1><<<dim3(32 * 8), 256, 0, stream>>>(ctx, nullptr, wo, out, nullptr, hs,
                                                nullptr, nullptr, nullptr, nullptr, Tt, 1024, 1024, 8);
    rmsnorm_k<<<dim3(Tt), 256, 0, stream>>>(out, ln2, h2);
    (void)hipMemsetAsync(counts, 0, 64, stream);
    router_k<<<dim3(Tt), 256, 0, stream>>>(h2, rw, probs, counts, tokl, gwl);
    finalize_k<<<dim3(1), 256, 0, stream>>>(probs, counts, offs, out + (size_t)Tt * Dd);
    // MoE: gate -> act ; up (fused silu*up*gate_w) ; down scatter-add into out
    gemm_k<2><<<dim3(32 * 32, En), 256, 0, stream>>>(h2, nullptr, wg, nullptr, act, nullptr,
                                                     tokl, gwl, counts, offs, Tt, Fn, Dd, 32);
    gemm_k<3><<<dim3(32 * 32, En), 256, 0, stream>>>(h2, nullptr, wu, nullptr, act, nullptr,
                                                     tokl, gwl, counts, offs, Tt, Fn, Dd, 32);
    gemm_k<4><<<dim3(32 * 8, En), 256, 0, stream>>>(nullptr, act, wd, out, nullptr, nullptr,
                                                    tokl, gwl, counts, offs, Tt, Dd, Fn, 8);
}

// Round 2
// 1335.673 us; speedup vs baseline: 1.1512x; 1.1512x over previous
//
#include <hip/hip_runtime.h>

#define Tt 4096
#define Bb 2
#define Ss 2048
#define Dd 1024
#define Hh 16
#define KVHn 4
#define HDn 64
#define En 8
#define Fn 4096

#define BM 128
#define BN 128
#define BK 32
#define LP 40   // LDS row stride (elems): 80B rows -> bank-conflict-free b128 frag reads

typedef unsigned short u16;
typedef __attribute__((ext_vector_type(4))) float f32x4;
typedef __attribute__((ext_vector_type(8))) short bfrag;
typedef __attribute__((ext_vector_type(4))) short s16x4;

__device__ __forceinline__ u16 f2bf(float f) {
    unsigned u = __builtin_bit_cast(unsigned, f);
    u = (u + 0x7fffu + ((u >> 16) & 1u)) >> 16;
    return (u16)u;
}
__device__ __forceinline__ float bf2f(u16 b) {
    unsigned u = ((unsigned)b) << 16;
    return __builtin_bit_cast(float, u);
}
__device__ __forceinline__ void split8a(const float* va, bfrag* ph, bfrag* pl) {
    bfrag th, tl;
#pragma unroll
    for (int j = 0; j < 8; j++) {
        u16 hu = f2bf(va[j]);
        th[j] = (short)hu;
        tl[j] = (short)f2bf(va[j] - bf2f(hu));
    }
    *ph = th; *pl = tl;
}

// ---------- transpose + bf16 convert (optionally hi/lo split): in f32 [K][N] -> out [N][K] ----------
template<bool SPL>
__global__ __launch_bounds__(256)
void tconv_k(const float* __restrict__ src, u16* __restrict__ dhi, u16* __restrict__ dlo,
             const int K, const int N, const int rowOff, const int nTilesN)
{
    const int tid = threadIdx.x;
    src += (size_t)blockIdx.y * K * N;
    dhi += (size_t)blockIdx.y * K * N;
    if (SPL) dlo += (size_t)blockIdx.y * K * N;
    const int ty = blockIdx.x / nTilesN, tx = blockIdx.x % nTilesN;
    const int k0 = ty * 64, n0 = tx * 64;
    __shared__ float tl[64][65];
#pragma unroll
    for (int it = 0; it < 16; it++) {
        int idx = tid + it * 256;
        int kk = idx >> 6, nn = idx & 63;
        tl[kk][nn] = src[(size_t)(k0 + kk) * N + n0 + nn];
    }
    __syncthreads();
#pragma unroll
    for (int it = 0; it < 8; it++) {
        int idx = tid + it * 256;
        int n = idx >> 5, k2 = (idx & 31) * 2;
        float v0 = tl[k2][n], v1 = tl[k2 + 1][n];
        u16 h0 = f2bf(v0), h1v = f2bf(v1);
        size_t o = (size_t)(rowOff + n0 + n) * K + k0 + k2;
        *(unsigned*)&dhi[o] = (unsigned)h0 | ((unsigned)h1v << 16);
        if (SPL) {
            u16 l0 = f2bf(v0 - bf2f(h0)), l1 = f2bf(v1 - bf2f(h1v));
            *(unsigned*)&dlo[o] = (unsigned)l0 | ((unsigned)l1 << 16);
        }
    }
}

// ---------- RMSNorm -> split bf16 (hi/lo) output ----------
__global__ __launch_bounds__(256)
void rmsnorm_split_k(const float* __restrict__ x, const float* __restrict__ w,
                     u16* __restrict__ ohi, u16* __restrict__ olo)
{
    const int row = blockIdx.x;
    const int tid = threadIdx.x;
    const int lane = tid & 63, wid = tid >> 6;
    f32x4 t4 = *(const f32x4*)(x + (size_t)row * Dd + tid * 4);
    float s = t4.x*t4.x + t4.y*t4.y + t4.z*t4.z + t4.w*t4.w;
#pragma unroll
    for (int o = 1; o < 64; o <<= 1) s += __shfl_xor(s, o, 64);
    __shared__ float red[4];
    if (lane == 0) red[wid] = s;
    __syncthreads();
    float inv = rsqrtf((red[0] + red[1] + red[2] + red[3]) * (1.0f / Dd) + 1e-6f);
    f32x4 w4 = *(const f32x4*)(w + tid * 4);
    float va[4] = { t4.x*inv*w4.x, t4.y*inv*w4.y, t4.z*inv*w4.z, t4.w*inv*w4.w };
    s16x4 hi, lo;
#pragma unroll
    for (int j = 0; j < 4; j++) {
        u16 hu = f2bf(va[j]);
        hi[j] = (short)hu;
        lo[j] = (short)f2bf(va[j] - bf2f(hu));
    }
    *(s16x4*)&ohi[(size_t)row * Dd + tid * 4] = hi;
    *(s16x4*)&olo[(size_t)row * Dd + tid * 4] = lo;
}

// ---------- RMSNorm -> f32 (router) + rounded bf16 (MoE A) ----------
__global__ __launch_bounds__(256)
void rmsnorm2_k(const float* __restrict__ x, const float* __restrict__ w,
                float* __restrict__ of, u16* __restrict__ ob)
{
    const int row = blockIdx.x;
    const int tid = threadIdx.x;
    const int lane = tid & 63, wid = tid >> 6;
    f32x4 t4 = *(const f32x4*)(x + (size_t)row * Dd + tid * 4);
    float s = t4.x*t4.x + t4.y*t4.y + t4.z*t4.z + t4.w*t4.w;
#pragma unroll
    for (int o = 1; o < 64; o <<= 1) s += __shfl_xor(s, o, 64);
    __shared__ float red[4];
    if (lane == 0) red[wid] = s;
    __syncthreads();
    float inv = rsqrtf((red[0] + red[1] + red[2] + red[3]) * (1.0f / Dd) + 1e-6f);
    f32x4 w4 = *(const f32x4*)(w + tid * 4);
    f32x4 o4;
    o4.x = t4.x*inv*w4.x; o4.y = t4.y*inv*w4.y; o4.z = t4.z*inv*w4.z; o4.w = t4.w*inv*w4.w;
    *(f32x4*)&of[(size_t)row * Dd + tid * 4] = o4;
    s16x4 hb;
    hb[0] = (short)f2bf(o4.x); hb[1] = (short)f2bf(o4.y);
    hb[2] = (short)f2bf(o4.z); hb[3] = (short)f2bf(o4.w);
    *(s16x4*)&ob[(size_t)row * Dd + tid * 4] = hb;
}

// ---------- RoPE tables (f64) ----------
__global__ __launch_bounds__(256)
void rope_tab_k(float* __restrict__ ct, float* __restrict__ st)
{
    int idx = blockIdx.x * 256 + threadIdx.x;
    if (idx < Ss * 32) {
        int s = idx >> 5, i = idx & 31;
        double inv = pow(10000.0, -((double)(2 * i)) / 64.0);
        double a = (double)s * inv;
        double sn, cs;
        sincos(a, &sn, &cs);
        ct[idx] = (float)cs;
        st[idx] = (float)sn;
    }
}

// ---------- RoPE on Q (in-place, qkv stride 1536) ----------
__global__ __launch_bounds__(256)
void rope_q_k(float* __restrict__ qkv, const float* __restrict__ ct, const float* __restrict__ st)
{
    int idx = blockIdx.x * 256 + threadIdx.x;  // Tt*Hh*32
    int i = idx & 31, hh = (idx >> 5) & (Hh - 1), t = idx >> 9;
    int s = t & (Ss - 1);
    float cs = ct[s * 32 + i], sn = st[s * 32 + i];
    float* base = qkv + (size_t)t * 1536 + hh * 64 + i;
    float x1 = base[0], x2 = base[32];
    base[0]  = x1 * cs - x2 * sn;
    base[32] = x2 * cs + x1 * sn;
}

// ---------- K: RoPE + split bf16 -> khi/klo [T][KVH*64] ----------
__global__ __launch_bounds__(256)
void kprep_k(const float* __restrict__ qkv, const float* __restrict__ ct,
             const float* __restrict__ st, u16* __restrict__ khi, u16* __restrict__ klo)
{
    int idx = blockIdx.x * 256 + threadIdx.x;  // Tt*KVHn*32
    int i = idx & 31, hh = (idx >> 5) & (KVHn - 1), t = idx >> 7;
    int s = t & (Ss - 1);
    float cs = ct[s * 32 + i], sn = st[s * 32 + i];
    const float* base = qkv + (size_t)t * 1536 + 1024 + hh * 64 + i;
    float x1 = base[0], x2 = base[32];
    float r1 = x1 * cs - x2 * sn, r2 = x2 * cs + x1 * sn;
    size_t o = (size_t)t * (KVHn * HDn) + hh * 64 + i;
    u16 h1v = f2bf(r1), h2v = f2bf(r2);
    khi[o] = h1v;       khi[o + 32] = h2v;
    klo[o] = f2bf(r1 - bf2f(h1v));
    klo[o + 32] = f2bf(r2 - bf2f(h2v));
}

// ---------- V: transpose + split -> vthi/vtlo [B*KVH][64 d][S] ----------
__global__ __launch_bounds__(256)
void vprep_k(const float* __restrict__ qkv, u16* __restrict__ vthi, u16* __restrict__ vtlo)
{
    const int st0 = blockIdx.x * 64;
    const int g = blockIdx.y;              // b*4 + kvh
    const int b = g >> 2, kvh = g & 3;
    const int tid = threadIdx.x;
    __shared__ float tl[64][65];
#pragma unroll
    for (int it = 0; it < 16; it++) {
        int idx = tid + it * 256;
        int sl = idx >> 6, d = idx & 63;
        tl[sl][d] = qkv[(size_t)(b * Ss + st0 + sl) * 1536 + 1280 + kvh * 64 + d];
    }
    __syncthreads();
#pragma unroll
    for (int it = 0; it < 8; it++) {
        int idx = tid + it * 256;
        int d = idx >> 5, s2 = (idx & 31) * 2;
        float v0 = tl[s2][d], v1 = tl[s2 + 1][d];
        u16 h0 = f2bf(v0), h1v = f2bf(v1);
        size_t o = ((size_t)g * 64 + d) * Ss + st0 + s2;
        *(unsigned*)&vthi[o] = (unsigned)h0 | ((unsigned)h1v << 16);
        u16 l0 = f2bf(v0 - bf2f(h0)), l1 = f2bf(v1 - bf2f(h1v));
        *(unsigned*)&vtlo[o] = (unsigned)l0 | ((unsigned)l1 << 16);
    }
}

// ---------- split-bf16x3 GEMM: C = A@B^T(+resid), A/B pre-split bf16 [rows][K] ----------
template<bool RESID>
__global__ __launch_bounds__(256)
void gemm_split_k(const u16* __restrict__ Ahi_g, const u16* __restrict__ Alo_g,
                  const u16* __restrict__ Bhi_g, const u16* __restrict__ Blo_g,
                  float* __restrict__ C, const float* __restrict__ resid,
                  const int M, const int N, const int K, const int ntiles)
{
    const int bid = blockIdx.x;
    const int nt = bid % ntiles, mt = bid / ntiles;
    __shared__ __align__(16) u16 Ah[BM * LP], Al[BM * LP], Bh[BN * LP], Bl[BN * LP];
    const int tid = threadIdx.x, lane = tid & 63, wid = tid >> 6;
    const int wrow = (wid >> 1) * 64, wcol = (wid & 1) * 64;
    const int l15 = lane & 15, lhi = lane >> 4;
    const int row0 = mt * BM, col0 = nt * BN;
    f32x4 acc[4][4];
#pragma unroll
    for (int i = 0; i < 4; i++)
#pragma unroll
        for (int j = 0; j < 4; j++) { acc[i][j].x = 0.f; acc[i][j].y = 0.f; acc[i][j].z = 0.f; acc[i][j].w = 0.f; }

    for (int k0 = 0; k0 < K; k0 += BK) {
#pragma unroll
        for (int it = 0; it < 2; it++) {
            int idx = tid + it * 256;
            int m = idx >> 2, kg = (idx & 3) * 8;
            size_t ga = (size_t)(row0 + m) * K + k0 + kg;
            *(bfrag*)&Ah[m * LP + kg] = *(const bfrag*)&Ahi_g[ga];
            *(bfrag*)&Al[m * LP + kg] = *(const bfrag*)&Alo_g[ga];
            size_t gb = (size_t)(col0 + m) * K + k0 + kg;
            *(bfrag*)&Bh[m * LP + kg] = *(const bfrag*)&Bhi_g[gb];
            *(bfrag*)&Bl[m * LP + kg] = *(const bfrag*)&Blo_g[gb];
        }
        __syncthreads();
        bfrag ah[4], al[4], bh[4], bl[4];
#pragma unroll
        for (int mi = 0; mi < 4; mi++) {
            int rb = (wrow + mi * 16 + l15) * LP + lhi * 8;
            ah[mi] = *(const bfrag*)&Ah[rb];
            al[mi] = *(const bfrag*)&Al[rb];
        }
#pragma unroll
        for (int ni = 0; ni < 4; ni++) {
            int rb = (wcol + ni * 16 + l15) * LP + lhi * 8;
            bh[ni] = *(const bfrag*)&Bh[rb];
            bl[ni] = *(const bfrag*)&Bl[rb];
        }
#pragma unroll
        for (int mi = 0; mi < 4; mi++)
#pragma unroll
            for (int ni = 0; ni < 4; ni++) {
                acc[mi][ni] = __builtin_amdgcn_mfma_f32_16x16x32_bf16(ah[mi], bh[ni], acc[mi][ni], 0, 0, 0);
                acc[mi][ni] = __builtin_amdgcn_mfma_f32_16x16x32_bf16(ah[mi], bl[ni], acc[mi][ni], 0, 0, 0);
                acc[mi][ni] = __builtin_amdgcn_mfma_f32_16x16x32_bf16(al[mi], bh[ni], acc[mi][ni], 0, 0, 0);
            }
        __syncthreads();
    }
#pragma unroll
    for (int mi = 0; mi < 4; mi++) {
#pragma unroll
        for (int t = 0; t < 4; t++) {
            int pr = row0 + wrow + mi * 16 + lhi * 4 + t;
#pragma unroll
            for (int ni = 0; ni < 4; ni++) {
                int gc = col0 + wcol + ni * 16 + l15;
                float vv = acc[mi][ni][t];
                if (RESID) vv += resid[(size_t)pr * N + gc];
                C[(size_t)pr * N + gc] = vv;
            }
        }
    }
}

// ---------- fused MoE gate+up: act = silu(A@Wg^T) * (A@Wu^T) * gate_w ----------
__global__ __launch_bounds__(256)
void gemm_gateup_k(const u16* __restrict__ A_g, const u16* __restrict__ Bg_g,
                   const u16* __restrict__ Bu_g, u16* __restrict__ act,
                   const int* __restrict__ toklist, const float* __restrict__ gwlist,
                   const int* __restrict__ counts, const int* __restrict__ offsets)
{
    const int e = blockIdx.y;
    const int Meff = counts[e];
    const int nt = blockIdx.x & 31, mt = blockIdx.x >> 5;
    if (mt * BM >= Meff) return;
    const int* tok = toklist + e * Tt;
    const float* gw = gwlist + e * Tt;
    const int rowoff = offsets[e];
    const u16* Bg = Bg_g + (size_t)e * Fn * Dd;
    const u16* Bu = Bu_g + (size_t)e * Fn * Dd;
    __shared__ __align__(16) u16 As[BM * LP], Gs[BN * LP], Us[BN * LP];
    const int tid = threadIdx.x, lane = tid & 63, wid = tid >> 6;
    const int wrow = (wid >> 1) * 64, wcol = (wid & 1) * 64;
    const int l15 = lane & 15, lhi = lane >> 4;
    const int row0 = mt * BM, col0 = nt * BN;
    f32x4 ag[4][4], au[4][4];
#pragma unroll
    for (int i = 0; i < 4; i++)
#pragma unroll
        for (int j = 0; j < 4; j++) {
            ag[i][j].x = 0.f; ag[i][j].y = 0.f; ag[i][j].z = 0.f; ag[i][j].w = 0.f;
            au[i][j].x = 0.f; au[i][j].y = 0.f; au[i][j].z = 0.f; au[i][j].w = 0.f;
        }
    for (int k0 = 0; k0 < Dd; k0 += BK) {
#pragma unroll
        for (int it = 0; it < 2; it++) {
            int idx = tid + it * 256;
            int m = idx >> 2, kg = (idx & 3) * 8;
            int pr = row0 + m;
            bfrag av = {0,0,0,0,0,0,0,0};
            if (pr < Meff) av = *(const bfrag*)&A_g[(size_t)tok[pr] * Dd + k0 + kg];
            *(bfrag*)&As[m * LP + kg] = av;
            size_t gb = (size_t)(col0 + m) * Dd + k0 + kg;
            *(bfrag*)&Gs[m * LP + kg] = *(const bfrag*)&Bg[gb];
            *(bfrag*)&Us[m * LP + kg] = *(const bfrag*)&Bu[gb];
        }
        __syncthreads();
        bfrag a[4], bg[4], bu[4];
#pragma unroll
        for (int mi = 0; mi < 4; mi++)
            a[mi] = *(const bfrag*)&As[(wrow + mi * 16 + l15) * LP + lhi * 8];
#pragma unroll
        for (int ni = 0; ni < 4; ni++) {
            int rb = (wcol + ni * 16 + l15) * LP + lhi * 8;
            bg[ni] = *(const bfrag*)&Gs[rb];
            bu[ni] = *(const bfrag*)&Us[rb];
        }
#pragma unroll
        for (int mi = 0; mi < 4; mi++)
#pragma unroll
            for (int ni = 0; ni < 4; ni++) {
                ag[mi][ni] = __builtin_amdgcn_mfma_f32_16x16x32_bf16(a[mi], bg[ni], ag[mi][ni], 0, 0, 0);
                au[mi][ni] = __builtin_amdgcn_mfma_f32_16x16x32_bf16(a[mi], bu[ni], au[mi][ni], 0, 0, 0);
            }
        __syncthreads();
    }
#pragma unroll
    for (int mi = 0; mi < 4; mi++) {
#pragma unroll
        for (int t = 0; t < 4; t++) {
            int pr = row0 + wrow + mi * 16 + lhi * 4 + t;
            if (pr < Meff) {
                float gwv = gw[pr];
#pragma unroll
                for (int ni = 0; ni < 4; ni++) {
                    int gc = col0 + wcol + ni * 16 + l15;
                    float g = ag[mi][ni][t], u = au[mi][ni][t];
                    float sg = g / (1.0f + expf(-g));
                    act[(size_t)(rowoff + pr) * Fn + gc] = f2bf(sg * u * gwv);
                }
            }
        }
    }
}

// ---------- MoE down: out[tok] += act @ Wd^T ----------
__global__ __launch_bounds__(256)
void gemm_down_k(const u16* __restrict__ act, const u16* __restrict__ Bd_g,
                 float* __restrict__ C, const int* __restrict__ toklist,
                 const int* __restrict__ counts, const int* __restrict__ offsets)
{
    const int e = blockIdx.y;
    const int Meff = counts[e];
    const int nt = blockIdx.x & 7, mt = blockIdx.x >> 3;
    if (mt * BM >= Meff) return;
    const int* tok = toklist + e * Tt;
    const int rowoff = offsets[e];
    const u16* Bd = Bd_g + (size_t)e * Dd * Fn;
    __shared__ __align__(16) u16 As[BM * LP], Bs[BN * LP];
    const int tid = threadIdx.x, lane = tid & 63, wid = tid >> 6;
    const int wrow = (wid >> 1) * 64, wcol = (wid & 1) * 64;
    const int l15 = lane & 15, lhi = lane >> 4;
    const int row0 = mt * BM, col0 = nt * BN;
    f32x4 acc[4][4];
#pragma unroll
    for (int i = 0; i < 4; i++)
#pragma unroll
        for (int j = 0; j < 4; j++) { acc[i][j].x = 0.f; acc[i][j].y = 0.f; acc[i][j].z = 0.f; acc[i][j].w = 0.f; }
    for (int k0 = 0; k0 < Fn; k0 += BK) {
#pragma unroll
        for (int it = 0; it < 2; it++) {
            int idx = tid + it * 256;
            int m = idx >> 2, kg = (idx & 3) * 8;
            int pr = row0 + m;
            bfrag av = {0,0,0,0,0,0,0,0};
            if (pr < Meff) av = *(const bfrag*)&act[(size_t)(rowoff + pr) * Fn + k0 + kg];
            *(bfrag*)&As[m * LP + kg] = av;
            *(bfrag*)&Bs[m * LP + kg] = *(const bfrag*)&Bd[(size_t)(col0 + m) * Fn + k0 + kg];
        }
        __syncthreads();
        bfrag a[4], b[4];
#pragma unroll
        for (int mi = 0; mi < 4; mi++)
            a[mi] = *(const bfrag*)&As[(wrow + mi * 16 + l15) * LP + lhi * 8];
#pragma unroll
        for (int ni = 0; ni < 4; ni++)
            b[ni] = *(const bfrag*)&Bs[(wcol + ni * 16 + l15) * LP + lhi * 8];
#pragma unroll
        for (int mi = 0; mi < 4; mi++)
#pragma unroll
            for (int ni = 0; ni < 4; ni++)
                acc[mi][ni] = __builtin_amdgcn_mfma_f32_16x16x32_bf16(a[mi], b[ni], acc[mi][ni], 0, 0, 0);
        __syncthreads();
    }
#pragma unroll
    for (int mi = 0; mi < 4; mi++) {
#pragma unroll
        for (int t = 0; t < 4; t++) {
            int pr = row0 + wrow + mi * 16 + lhi * 4 + t;
            if (pr < Meff) {
                int trow = tok[pr];
#pragma unroll
                for (int ni = 0; ni < 4; ni++) {
                    int gc = col0 + wcol + ni * 16 + l15;
                    atomicAdd(&C[(size_t)trow * Dd + gc], acc[mi][ni][t]);
                }
            }
        }
    }
}

// ---------- Flash attention (causal GQA), split-bf16x3, bf16 staged K/V ----------
__global__ __launch_bounds__(256)
void attn_k(const float* __restrict__ qkv, const u16* __restrict__ khi,
            const u16* __restrict__ klo, const u16* __restrict__ vthi,
            const u16* __restrict__ vtlo, u16* __restrict__ chi, u16* __restrict__ clo)
{
    const int qt = (int)gridDim.x - 1 - (int)blockIdx.x;   // longest blocks first
    const int h = blockIdx.y, b = blockIdx.z;
    const int kvh = h >> 2;
    const int g = b * KVHn + kvh;
    const int tid = threadIdx.x;
    const int lane = tid & 63, wid = tid >> 6;
    const int l15 = lane & 15, lhi = lane >> 4;

    __shared__ __align__(16) u16 Khi[64 * 64];
    __shared__ __align__(16) u16 Klo[64 * 64];
    __shared__ __align__(16) u16 Vhi[64 * 72];
    __shared__ __align__(16) u16 Vlo[64 * 72];
    __shared__ __align__(16) u16 Phi[4 * 16 * 72];
    __shared__ __align__(16) u16 Plo[4 * 16 * 72];

    bfrag qh[2], ql[2];
    {
        const int qrow = qt * 64 + wid * 16 + l15;
        const float* qb = qkv + (size_t)(b * Ss + qrow) * 1536 + h * 64;
#pragma unroll
        for (int ks = 0; ks < 2; ks++) {
            const float* p = qb + ks * 32 + lhi * 8;
            f32x4 u0 = *(const f32x4*)p;
            f32x4 u1 = *(const f32x4*)(p + 4);
            float va[8] = { u0.x * 0.125f, u0.y * 0.125f, u0.z * 0.125f, u0.w * 0.125f,
                            u1.x * 0.125f, u1.y * 0.125f, u1.z * 0.125f, u1.w * 0.125f };
            split8a(va, &qh[ks], &ql[ks]);
        }
    }
    f32x4 O[4];
#pragma unroll
    for (int ni = 0; ni < 4; ni++) { O[ni].x = 0.f; O[ni].y = 0.f; O[ni].z = 0.f; O[ni].w = 0.f; }
    float m_r[4] = { -1e30f, -1e30f, -1e30f, -1e30f };
    float l_r[4] = { 0.f, 0.f, 0.f, 0.f };

    for (int kt = 0; kt <= qt; kt++) {
        // ---- stage K tile (bf16, XOR-swizzled rows) ----
#pragma unroll
        for (int it = 0; it < 2; it++) {
            int ci = tid + it * 256;
            int kv = ci >> 3, d0 = (ci & 7) << 3;
            size_t ga = (size_t)(b * Ss + kt * 64 + kv) * (KVHn * HDn) + kvh * 64 + d0;
            int boff = kv * 128 + ((d0 * 2) ^ ((kv & 7) << 4));
            *(bfrag*)((char*)Khi + boff) = *(const bfrag*)&khi[ga];
            *(bfrag*)((char*)Klo + boff) = *(const bfrag*)&klo[ga];
        }
        // ---- stage V^T tile (bf16, coalesced rows) ----
#pragma unroll
        for (int it = 0; it < 2; it++) {
            int ci = tid + it * 256;
            int d = ci >> 3, kv0 = (ci & 7) << 3;
            size_t ga = ((size_t)g * 64 + d) * Ss + kt * 64 + kv0;
            *(bfrag*)&Vhi[d * 72 + kv0] = *(const bfrag*)&vthi[ga];
            *(bfrag*)&Vlo[d * 72 + kv0] = *(const bfrag*)&vtlo[ga];
        }
        __syncthreads();
        // ---- S = Q K^T (3-pass split) ----
        f32x4 sf[4];
#pragma unroll
        for (int ni = 0; ni < 4; ni++) { sf[ni].x = 0.f; sf[ni].y = 0.f; sf[ni].z = 0.f; sf[ni].w = 0.f; }
#pragma unroll
        for (int ks = 0; ks < 2; ks++) {
#pragma unroll
            for (int ni = 0; ni < 4; ni++) {
                int kv = ni * 16 + l15;
                int dof = ks * 64 + lhi * 16;
                int boff = kv * 128 + (dof ^ ((kv & 7) << 4));
                bfrag kfh = *(const bfrag*)((const char*)Khi + boff);
                bfrag kfl = *(const bfrag*)((const char*)Klo + boff);
                sf[ni] = __builtin_amdgcn_mfma_f32_16x16x32_bf16(qh[ks], kfh, sf[ni], 0, 0, 0);
                sf[ni] = __builtin_amdgcn_mfma_f32_16x16x32_bf16(qh[ks], kfl, sf[ni], 0, 0, 0);
                sf[ni] = __builtin_amdgcn_mfma_f32_16x16x32_bf16(ql[ks], kfh, sf[ni], 0, 0, 0);
            }
        }
        if (kt == qt) {
#pragma unroll
            for (int ni = 0; ni < 4; ni++)
#pragma unroll
                for (int t = 0; t < 4; t++)
                    if (ni * 16 + l15 > wid * 16 + lhi * 4 + t) sf[ni][t] = -1e30f;
        }
        float sfac[4];
#pragma unroll
        for (int t = 0; t < 4; t++) {
            float mx = fmaxf(fmaxf(sf[0][t], sf[1][t]), fmaxf(sf[2][t], sf[3][t]));
#pragma unroll
            for (int o = 1; o < 16; o <<= 1) mx = fmaxf(mx, __shfl_xor(mx, o, 64));
            float mn = fmaxf(m_r[t], mx);
            float sc = expf(m_r[t] - mn);
            m_r[t] = mn;
            float rs = 0.f;
#pragma unroll
            for (int ni = 0; ni < 4; ni++) {
                float p = expf(sf[ni][t] - mn);
                sf[ni][t] = p;
                rs += p;
            }
#pragma unroll
            for (int o = 1; o < 16; o <<= 1) rs += __shfl_xor(rs, o, 64);
            l_r[t] = l_r[t] * sc + rs;
            sfac[t] = sc;
        }
#pragma unroll
        for (int ni = 0; ni < 4; ni++)
#pragma unroll
            for (int t = 0; t < 4; t++) O[ni][t] *= sfac[t];
#pragma unroll
        for (int ni = 0; ni < 4; ni++)
#pragma unroll
            for (int t = 0; t < 4; t++) {
                float p = sf[ni][t];
                u16 hu = f2bf(p);
                int ix = (wid * 16 + lhi * 4 + t) * 72 + ni * 16 + l15;
                Phi[ix] = hu;
                Plo[ix] = f2bf(p - bf2f(hu));
            }
        __syncthreads();
#pragma unroll
        for (int ks = 0; ks < 2; ks++) {
            int pb = (wid * 16 + l15) * 72 + ks * 32 + lhi * 8;
            bfrag pfh = *(const bfrag*)&Phi[pb];
            bfrag pfl = *(const bfrag*)&Plo[pb];
#pragma unroll
            for (int ni = 0; ni < 4; ni++) {
                int vb = (ni * 16 + l15) * 72 + ks * 32 + lhi * 8;
                bfrag vfh = *(const bfrag*)&Vhi[vb];
                bfrag vfl = *(const bfrag*)&Vlo[vb];
                O[ni] = __builtin_amdgcn_mfma_f32_16x16x32_bf16(pfh, vfh, O[ni], 0, 0, 0);
                O[ni] = __builtin_amdgcn_mfma_f32_16x16x32_bf16(pfh, vfl, O[ni], 0, 0, 0);
                O[ni] = __builtin_amdgcn_mfma_f32_16x16x32_bf16(pfl, vfh, O[ni], 0, 0, 0);
            }
        }
        __syncthreads();
    }
#pragma unroll
    for (int t = 0; t < 4; t++) {
        float inv = 1.0f / l_r[t];
        int qrow = qt * 64 + wid * 16 + lhi * 4 + t;
        size_t base = (size_t)(b * Ss + qrow) * Dd + h * 64;
#pragma unroll
        for (int ni = 0; ni < 4; ni++) {
            float val = O[ni][t] * inv;
            u16 hv = f2bf(val);
            chi[base + ni * 16 + l15] = hv;
            clo[base + ni * 16 + l15] = f2bf(val - bf2f(hv));
        }
    }
}

// ---------- Router ----------
__global__ __launch_bounds__(256)
void router_k(const float* __restrict__ h2, const float* __restrict__ rw,
              float* __restrict__ probs, int* __restrict__ counts,
              int* __restrict__ toklist, float* __restrict__ gwlist)
{
    const int t = blockIdx.x;
    const int tid = threadIdx.x;
    const int lane = tid & 63, wid = tid >> 6;
    f32x4 x4 = *(const f32x4*)(h2 + (size_t)t * Dd + tid * 4);
    float part[En];
#pragma unroll
    for (int e = 0; e < En; e++) {
        f32x4 w4 = *(const f32x4*)(rw + (size_t)e * Dd + tid * 4);
        part[e] = x4.x * w4.x + x4.y * w4.y + x4.z * w4.z + x4.w * w4.w;
    }
#pragma unroll
    for (int e = 0; e < En; e++)
#pragma unroll
        for (int o = 1; o < 64; o <<= 1) part[e] += __shfl_xor(part[e], o, 64);
    __shared__ float red[4][En];
    if (lane == 0) {
#pragma unroll
        for (int e = 0; e < En; e++) red[wid][e] = part[e];
    }
    __syncthreads();
    if (tid == 0) {
        float lg[En];
        float mx = -1e30f;
#pragma unroll
        for (int e = 0; e < En; e++) {
            lg[e] = red[0][e] + red[1][e] + red[2][e] + red[3][e];
            mx = fmaxf(mx, lg[e]);
        }
        float pe[En], ssum = 0.f;
#pragma unroll
        for (int e = 0; e < En; e++) { pe[e] = expf(lg[e] - mx); ssum += pe[e]; }
        float inv = 1.0f / ssum;
#pragma unroll
        for (int e = 0; e < En; e++) { pe[e] *= inv; probs[(size_t)t * En + e] = pe[e]; }
        int i0 = 0;
#pragma unroll
        for (int e = 1; e < En; e++) if (pe[e] > pe[i0]) i0 = e;
        int i1 = (i0 == 0) ? 1 : 0;
#pragma unroll
        for (int e = 0; e < En; e++) if (e != i0 && pe[e] > pe[i1]) i1 = e;
        float s2 = pe[i0] + pe[i1];
        int s0 = atomicAdd(&counts[i0], 1);
        toklist[i0 * Tt + s0] = t; gwlist[i0 * Tt + s0] = pe[i0] / s2;
        int s1 = atomicAdd(&counts[i1], 1);
        toklist[i1 * Tt + s1] = t; gwlist[i1 * Tt + s1] = pe[i1] / s2;
    }
}

// ---------- offsets + balance loss ----------
__global__ __launch_bounds__(256)
void finalize_k(const float* __restrict__ probs, const int* __restrict__ counts,
                int* __restrict__ offsets, float* __restrict__ loss_out)
{
    const int tid = threadIdx.x, lane = tid & 63, wid = tid >> 6;
    float ps[En];
#pragma unroll
    for (int e = 0; e < En; e++) ps[e] = 0.f;
    for (int t = tid; t < Tt; t += 256) {
#pragma unroll
        for (int e = 0; e < En; e++) ps[e] += probs[(size_t)t * En + e];
    }
#pragma unroll
    for (int e = 0; e < En; e++)
#pragma unroll
        for (int o = 1; o < 64; o <<= 1) ps[e] += __shfl_xor(ps[e], o, 64);
    __shared__ float red[4][En];
    if (lane == 0) {
#pragma unroll
        for (int e = 0; e < En; e++) red[wid][e] = ps[e];
    }
    __syncthreads();
    if (tid == 0) {
        int o = 0;
        float bl = 0.f;
#pragma unroll
        for (int e = 0; e < En; e++) {
            offsets[e] = o; o += counts[e];
            float pm = (red[0][e] + red[1][e] + red[2][e] + red[3][e]) * (1.0f / Tt);
            float fr = (float)counts[e] * (1.0f / (Tt * 2));
            bl += fr * pm;
        }
        loss_out[0] = 0.01f * (float)En * bl;
    }
}

extern "C" void kernel_launch(void* const* d_in, const int* in_sizes, int n_in,
                              void* d_out, int out_size, void* d_ws, size_t ws_size,
                              hipStream_t stream)
{
    (void)in_sizes; (void)n_in; (void)out_size; (void)ws_size;
    const float* hs  = (const float*)d_in[0];
    const float* ln1 = (const float*)d_in[1];
    const float* wq  = (const float*)d_in[2];
    const float* wk  = (const float*)d_in[3];
    const float* wv  = (const float*)d_in[4];
    const float* wo  = (const float*)d_in[5];
    const float* ln2 = (const float*)d_in[6];
    const float* rw  = (const float*)d_in[7];
    const float* wg  = (const float*)d_in[8];
    const float* wu  = (const float*)d_in[9];
    const float* wd  = (const float*)d_in[10];
    float* out = (float*)d_out;

    char* ws = (char*)d_ws;
    size_t off = 0;
    auto nxt = [&](size_t bytes) { char* p = ws + off; off += (bytes + 255) & ~(size_t)255; return p; };
    // ---- persistent (MoE-era) region ----
    u16* wgt  = (u16*)nxt((size_t)En * Fn * Dd * 2);
    u16* wut  = (u16*)nxt((size_t)En * Fn * Dd * 2);
    u16* wdt  = (u16*)nxt((size_t)En * Dd * Fn * 2);
    float* h2 = (float*)nxt((size_t)Tt * Dd * 4);
    u16* h2b  = (u16*)nxt((size_t)Tt * Dd * 2);
    float* probs = (float*)nxt((size_t)Tt * En * 4);
    int*   tokl  = (int*)nxt((size_t)En * Tt * 4);
    float* gwl   = (float*)nxt((size_t)En * Tt * 4);
    float* ctab  = (float*)nxt((size_t)Ss * 32 * 4);
    float* stab  = (float*)nxt((size_t)Ss * 32 * 4);
    int* counts  = (int*)nxt(256);
    int* offs    = (int*)nxt(256);
    // ---- transient (pre-MoE) region; `act` aliases it ----
    u16* act = (u16*)(ws + off);                     // 2*Tt*Fn*2 = 67.1 MB, alias OK
    float* qkv = (float*)nxt((size_t)Tt * 1536 * 4);
    u16* h1hi = (u16*)nxt((size_t)Tt * Dd * 2);
    u16* h1lo = (u16*)nxt((size_t)Tt * Dd * 2);
    u16* khi  = (u16*)nxt((size_t)Tt * KVHn * HDn * 2);
    u16* klo  = (u16*)nxt((size_t)Tt * KVHn * HDn * 2);
    u16* vthi = (u16*)nxt((size_t)Tt * KVHn * HDn * 2);
    u16* vtlo = (u16*)nxt((size_t)Tt * KVHn * HDn * 2);
    u16* chi  = (u16*)nxt((size_t)Tt * Dd * 2);
    u16* clo  = (u16*)nxt((size_t)Tt * Dd * 2);
    u16* wqkvthi = (u16*)nxt((size_t)1536 * Dd * 2);
    u16* wqkvtlo = (u16*)nxt((size_t)1536 * Dd * 2);
    u16* wothi = (u16*)nxt((size_t)Dd * Dd * 2);
    u16* wotlo = (u16*)nxt((size_t)Dd * Dd * 2);

    rope_tab_k<<<dim3(256), 256, 0, stream>>>(ctab, stab);
    // weight prep (transpose + convert)
    tconv_k<true ><<<dim3(16 * 16), 256, 0, stream>>>(wq, wqkvthi, wqkvtlo, 1024, 1024,    0, 16);
    tconv_k<true ><<<dim3(16 *  4), 256, 0, stream>>>(wk, wqkvthi, wqkvtlo, 1024,  256, 1024,  4);
    tconv_k<true ><<<dim3(16 *  4), 256, 0, stream>>>(wv, wqkvthi, wqkvtlo, 1024,  256, 1280,  4);
    tconv_k<true ><<<dim3(16 * 16), 256, 0, stream>>>(wo, wothi, wotlo, 1024, 1024, 0, 16);
    tconv_k<false><<<dim3(16 * 64, En), 256, 0, stream>>>(wg, wgt, nullptr, 1024, 4096, 0, 64);
    tconv_k<false><<<dim3(16 * 64, En), 256, 0, stream>>>(wu, wut, nullptr, 1024, 4096, 0, 64);
    tconv_k<false><<<dim3(64 * 16, En), 256, 0, stream>>>(wd, wdt, nullptr, 4096, 1024, 0, 16);

    rmsnorm_split_k<<<dim3(Tt), 256, 0, stream>>>(hs, ln1, h1hi, h1lo);
    gemm_split_k<false><<<dim3(12 * 32), 256, 0, stream>>>(h1hi, h1lo, wqkvthi, wqkvtlo,
                                                           qkv, nullptr, Tt, 1536, Dd, 12);
    rope_q_k<<<dim3(Tt * Hh * 32 / 256), 256, 0, stream>>>(qkv, ctab, stab);
    kprep_k<<<dim3(Tt * KVHn * 32 / 256), 256, 0, stream>>>(qkv, ctab, stab, khi, klo);
    vprep_k<<<dim3(Ss / 64, Bb * KVHn), 256, 0, stream>>>(qkv, vthi, vtlo);
    attn_k<<<dim3(Ss / 64, Hh, Bb), 256, 0, stream>>>(qkv, khi, klo, vthi, vtlo, chi, clo);
    gemm_split_k<true><<<dim3(8 * 32), 256, 0, stream>>>(chi, clo, wothi, wotlo,
                                                         out, hs, Tt, Dd, Dd, 8);
    rmsnorm2_k<<<dim3(Tt), 256, 0, stream>>>(out, ln2, h2, h2b);
    (void)hipMemsetAsync(counts, 0, 64, stream);
    router_k<<<dim3(Tt), 256, 0, stream>>>(h2, rw, probs, counts, tokl, gwl);
    finalize_k<<<dim3(1), 256, 0, stream>>>(probs, counts, offs, out + (size_t)Tt * Dd);
    gemm_gateup_k<<<dim3(32 * 32, En), 256, 0, stream>>>(h2b, wgt, wut, act, tokl, gwl, counts, offs);
    gemm_down_k<<<dim3(8 * 32, En), 256, 0, stream>>>(act, wdt, out, tokl, counts, offs);
}

// Round 3
// 1085.302 us; speedup vs baseline: 1.4167x; 1.2307x over previous
//
#include <hip/hip_runtime.h>

#define Tt 4096
#define Bb 2
#define Ss 2048
#define Dd 1024
#define Hh 16
#define KVHn 4
#define HDn 64
#define En 8
#define Fn 4096

#define BM 128
#define BN 128
#define LP 40   // LDS row stride for the split GEMMs (reg-staged path)

typedef unsigned short u16;
typedef __attribute__((ext_vector_type(4))) float f32x4;
typedef __attribute__((ext_vector_type(8))) short bfrag;
typedef __attribute__((ext_vector_type(4))) short s16x4;

__device__ __forceinline__ u16 f2bf(float f) {
    unsigned u = __builtin_bit_cast(unsigned, f);
    u = (u + 0x7fffu + ((u >> 16) & 1u)) >> 16;
    return (u16)u;
}
__device__ __forceinline__ float bf2f(u16 b) {
    unsigned u = ((unsigned)b) << 16;
    return __builtin_bit_cast(float, u);
}
__device__ __forceinline__ void split8a(const float* va, bfrag* ph, bfrag* pl) {
    bfrag th, tl;
#pragma unroll
    for (int j = 0; j < 8; j++) {
        u16 hu = f2bf(va[j]);
        th[j] = (short)hu;
        tl[j] = (short)f2bf(va[j] - bf2f(hu));
    }
    *ph = th; *pl = tl;
}
// async global->LDS, 16B per lane; LDS dest = wave-uniform base + lane*16, global src per-lane
__device__ __forceinline__ void glds16(const void* g, void* l) {
    __builtin_amdgcn_global_load_lds(
        (const __attribute__((address_space(1))) unsigned int*)g,
        (__attribute__((address_space(3))) unsigned int*)l, 16, 0, 0);
}

// ---------- transpose + bf16 convert (hi/lo split) for QKV/WO weights: [K][N] -> [N][K] ----------
template<bool SPL>
__global__ __launch_bounds__(256)
void tconv_k(const float* __restrict__ src, u16* __restrict__ dhi, u16* __restrict__ dlo,
             const int K, const int N, const int rowOff, const int nTilesN)
{
    const int tid = threadIdx.x;
    const int ty = blockIdx.x / nTilesN, tx = blockIdx.x % nTilesN;
    const int k0 = ty * 64, n0 = tx * 64;
    __shared__ float tl[64][65];
#pragma unroll
    for (int it = 0; it < 16; it++) {
        int idx = tid + it * 256;
        int kk = idx >> 6, nn = idx & 63;
        tl[kk][nn] = src[(size_t)(k0 + kk) * N + n0 + nn];
    }
    __syncthreads();
#pragma unroll
    for (int it = 0; it < 8; it++) {
        int idx = tid + it * 256;
        int n = idx >> 5, k2 = (idx & 31) * 2;
        float v0 = tl[k2][n], v1 = tl[k2 + 1][n];
        u16 h0 = f2bf(v0), h1v = f2bf(v1);
        size_t o = (size_t)(rowOff + n0 + n) * K + k0 + k2;
        *(unsigned*)&dhi[o] = (unsigned)h0 | ((unsigned)h1v << 16);
        if (SPL) {
            u16 l0 = f2bf(v0 - bf2f(h0)), l1 = f2bf(v1 - bf2f(h1v));
            *(unsigned*)&dlo[o] = (unsigned)l0 | ((unsigned)l1 << 16);
        }
    }
}

// ---------- MoE weight prep: f32 [K][N] -> tiled bf16 blocks [nt][kt][128n x TBK k] ----------
// Block internal layout == LDS image: elem (n, kl) chunk c=kl/8 stored at byte
// n*TBK*2 + ((c*16) ^ (SWZ ? ((n&7)<<4) : 0)).
template<int TBK, bool SWZ>
__global__ __launch_bounds__(256)
void tprep_k(const float* __restrict__ src, u16* __restrict__ dst,
             const int K, const int N, const int nTilesN)
{
    const int tid = threadIdx.x;
    const int e = blockIdx.y;
    const int ntl = blockIdx.x % nTilesN, kt = blockIdx.x / nTilesN;
    const int nTK = K / TBK;
    src += (size_t)e * K * N + (size_t)(kt * TBK) * N + ntl * 128;
    u16* dblk = dst + (((size_t)e * nTilesN + ntl) * nTK + kt) * (size_t)(128 * TBK);
    __shared__ float tl[TBK][132];
#pragma unroll
    for (int it = 0; it < TBK / 8; it++) {
        int i4 = tid + it * 256;
        int kk = i4 >> 5, n = (i4 & 31) * 4;
        f32x4 v = *(const f32x4*)(src + (size_t)kk * N + n);
        tl[kk][n] = v.x; tl[kk][n + 1] = v.y; tl[kk][n + 2] = v.z; tl[kk][n + 3] = v.w;
    }
    __syncthreads();
#pragma unroll
    for (int it = 0; it < TBK / 16; it++) {
        int idx = tid + it * 256;
        int n = (TBK == 32) ? (idx >> 2) : (idx >> 3);
        int c = (TBK == 32) ? (idx & 3) : (idx & 7);
        bfrag v;
#pragma unroll
        for (int j = 0; j < 8; j++) v[j] = (short)f2bf(tl[c * 8 + j][n]);
        int boff = n * (TBK * 2) + ((c * 16) ^ (SWZ ? ((n & 7) << 4) : 0));
        *(bfrag*)((char*)dblk + boff) = v;
    }
}

// ---------- RMSNorm -> split bf16 (hi/lo) ----------
__global__ __launch_bounds__(256)
void rmsnorm_split_k(const float* __restrict__ x, const float* __restrict__ w,
                     u16* __restrict__ ohi, u16* __restrict__ olo)
{
    const int row = blockIdx.x;
    const int tid = threadIdx.x;
    const int lane = tid & 63, wid = tid >> 6;
    f32x4 t4 = *(const f32x4*)(x + (size_t)row * Dd + tid * 4);
    float s = t4.x*t4.x + t4.y*t4.y + t4.z*t4.z + t4.w*t4.w;
#pragma unroll
    for (int o = 1; o < 64; o <<= 1) s += __shfl_xor(s, o, 64);
    __shared__ float red[4];
    if (lane == 0) red[wid] = s;
    __syncthreads();
    float inv = rsqrtf((red[0] + red[1] + red[2] + red[3]) * (1.0f / Dd) + 1e-6f);
    f32x4 w4 = *(const f32x4*)(w + tid * 4);
    float va[4] = { t4.x*inv*w4.x, t4.y*inv*w4.y, t4.z*inv*w4.z, t4.w*inv*w4.w };
    s16x4 hi, lo;
#pragma unroll
    for (int j = 0; j < 4; j++) {
        u16 hu = f2bf(va[j]);
        hi[j] = (short)hu;
        lo[j] = (short)f2bf(va[j] - bf2f(hu));
    }
    *(s16x4*)&ohi[(size_t)row * Dd + tid * 4] = hi;
    *(s16x4*)&olo[(size_t)row * Dd + tid * 4] = lo;
}

// ---------- RMSNorm -> f32 (router) + rounded bf16 (MoE A) ----------
__global__ __launch_bounds__(256)
void rmsnorm2_k(const float* __restrict__ x, const float* __restrict__ w,
                float* __restrict__ of, u16* __restrict__ ob)
{
    const int row = blockIdx.x;
    const int tid = threadIdx.x;
    const int lane = tid & 63, wid = tid >> 6;
    f32x4 t4 = *(const f32x4*)(x + (size_t)row * Dd + tid * 4);
    float s = t4.x*t4.x + t4.y*t4.y + t4.z*t4.z + t4.w*t4.w;
#pragma unroll
    for (int o = 1; o < 64; o <<= 1) s += __shfl_xor(s, o, 64);
    __shared__ float red[4];
    if (lane == 0) red[wid] = s;
    __syncthreads();
    float inv = rsqrtf((red[0] + red[1] + red[2] + red[3]) * (1.0f / Dd) + 1e-6f);
    f32x4 w4 = *(const f32x4*)(w + tid * 4);
    f32x4 o4;
    o4.x = t4.x*inv*w4.x; o4.y = t4.y*inv*w4.y; o4.z = t4.z*inv*w4.z; o4.w = t4.w*inv*w4.w;
    *(f32x4*)&of[(size_t)row * Dd + tid * 4] = o4;
    s16x4 hb;
    hb[0] = (short)f2bf(o4.x); hb[1] = (short)f2bf(o4.y);
    hb[2] = (short)f2bf(o4.z); hb[3] = (short)f2bf(o4.w);
    *(s16x4*)&ob[(size_t)row * Dd + tid * 4] = hb;
}

// ---------- RoPE tables (f64) ----------
__global__ __launch_bounds__(256)
void rope_tab_k(float* __restrict__ ct, float* __restrict__ st)
{
    int idx = blockIdx.x * 256 + threadIdx.x;
    if (idx < Ss * 32) {
        int s = idx >> 5, i = idx & 31;
        double inv = pow(10000.0, -((double)(2 * i)) / 64.0);
        double a = (double)s * inv;
        double sn, cs;
        sincos(a, &sn, &cs);
        ct[idx] = (float)cs;
        st[idx] = (float)sn;
    }
}

// ---------- RoPE on Q (in-place, qkv stride 1536) ----------
__global__ __launch_bounds__(256)
void rope_q_k(float* __restrict__ qkv, const float* __restrict__ ct, const float* __restrict__ st)
{
    int idx = blockIdx.x * 256 + threadIdx.x;
    int i = idx & 31, hh = (idx >> 5) & (Hh - 1), t = idx >> 9;
    int s = t & (Ss - 1);
    float cs = ct[s * 32 + i], sn = st[s * 32 + i];
    float* base = qkv + (size_t)t * 1536 + hh * 64 + i;
    float x1 = base[0], x2 = base[32];
    base[0]  = x1 * cs - x2 * sn;
    base[32] = x2 * cs + x1 * sn;
}

// ---------- K: RoPE + split bf16 ----------
__global__ __launch_bounds__(256)
void kprep_k(const float* __restrict__ qkv, const float* __restrict__ ct,
             const float* __restrict__ st, u16* __restrict__ khi, u16* __restrict__ klo)
{
    int idx = blockIdx.x * 256 + threadIdx.x;
    int i = idx & 31, hh = (idx >> 5) & (KVHn - 1), t = idx >> 7;
    int s = t & (Ss - 1);
    float cs = ct[s * 32 + i], sn = st[s * 32 + i];
    const float* base = qkv + (size_t)t * 1536 + 1024 + hh * 64 + i;
    float x1 = base[0], x2 = base[32];
    float r1 = x1 * cs - x2 * sn, r2 = x2 * cs + x1 * sn;
    size_t o = (size_t)t * (KVHn * HDn) + hh * 64 + i;
    u16 h1v = f2bf(r1), h2v = f2bf(r2);
    khi[o] = h1v;       khi[o + 32] = h2v;
    klo[o] = f2bf(r1 - bf2f(h1v));
    klo[o + 32] = f2bf(r2 - bf2f(h2v));
}

// ---------- V: transpose + split ----------
__global__ __launch_bounds__(256)
void vprep_k(const float* __restrict__ qkv, u16* __restrict__ vthi, u16* __restrict__ vtlo)
{
    const int st0 = blockIdx.x * 64;
    const int g = blockIdx.y;
    const int b = g >> 2, kvh = g & 3;
    const int tid = threadIdx.x;
    __shared__ float tl[64][65];
#pragma unroll
    for (int it = 0; it < 16; it++) {
        int idx = tid + it * 256;
        int sl = idx >> 6, d = idx & 63;
        tl[sl][d] = qkv[(size_t)(b * Ss + st0 + sl) * 1536 + 1280 + kvh * 64 + d];
    }
    __syncthreads();
#pragma unroll
    for (int it = 0; it < 8; it++) {
        int idx = tid + it * 256;
        int d = idx >> 5, s2 = (idx & 31) * 2;
        float v0 = tl[s2][d], v1 = tl[s2 + 1][d];
        u16 h0 = f2bf(v0), h1v = f2bf(v1);
        size_t o = ((size_t)g * 64 + d) * Ss + st0 + s2;
        *(unsigned*)&vthi[o] = (unsigned)h0 | ((unsigned)h1v << 16);
        u16 l0 = f2bf(v0 - bf2f(h0)), l1 = f2bf(v1 - bf2f(h1v));
        *(unsigned*)&vtlo[o] = (unsigned)l0 | ((unsigned)l1 << 16);
    }
}

// ---------- split-bf16x3 GEMM: C = A@B^T(+resid) ----------
template<bool RESID>
__global__ __launch_bounds__(256)
void gemm_split_k(const u16* __restrict__ Ahi_g, const u16* __restrict__ Alo_g,
                  const u16* __restrict__ Bhi_g, const u16* __restrict__ Blo_g,
                  float* __restrict__ C, const float* __restrict__ resid,
                  const int M, const int N, const int K, const int ntiles)
{
    const int bid = blockIdx.x;
    const int nt = bid % ntiles, mt = bid / ntiles;
    __shared__ __align__(16) u16 Ah[BM * LP], Al[BM * LP], Bh[BN * LP], Bl[BN * LP];
    const int tid = threadIdx.x, lane = tid & 63, wid = tid >> 6;
    const int wrow = (wid >> 1) * 64, wcol = (wid & 1) * 64;
    const int l15 = lane & 15, lhi = lane >> 4;
    const int row0 = mt * BM, col0 = nt * BN;
    f32x4 acc[4][4];
#pragma unroll
    for (int i = 0; i < 4; i++)
#pragma unroll
        for (int j = 0; j < 4; j++) { acc[i][j].x = 0.f; acc[i][j].y = 0.f; acc[i][j].z = 0.f; acc[i][j].w = 0.f; }

    for (int k0 = 0; k0 < K; k0 += 32) {
#pragma unroll
        for (int it = 0; it < 2; it++) {
            int idx = tid + it * 256;
            int m = idx >> 2, kg = (idx & 3) * 8;
            size_t ga = (size_t)(row0 + m) * K + k0 + kg;
            *(bfrag*)&Ah[m * LP + kg] = *(const bfrag*)&Ahi_g[ga];
            *(bfrag*)&Al[m * LP + kg] = *(const bfrag*)&Alo_g[ga];
            size_t gb = (size_t)(col0 + m) * K + k0 + kg;
            *(bfrag*)&Bh[m * LP + kg] = *(const bfrag*)&Bhi_g[gb];
            *(bfrag*)&Bl[m * LP + kg] = *(const bfrag*)&Blo_g[gb];
        }
        __syncthreads();
        bfrag ah[4], al[4], bh[4], bl[4];
#pragma unroll
        for (int mi = 0; mi < 4; mi++) {
            int rb = (wrow + mi * 16 + l15) * LP + lhi * 8;
            ah[mi] = *(const bfrag*)&Ah[rb];
            al[mi] = *(const bfrag*)&Al[rb];
        }
#pragma unroll
        for (int ni = 0; ni < 4; ni++) {
            int rb = (wcol + ni * 16 + l15) * LP + lhi * 8;
            bh[ni] = *(const bfrag*)&Bh[rb];
            bl[ni] = *(const bfrag*)&Bl[rb];
        }
#pragma unroll
        for (int mi = 0; mi < 4; mi++)
#pragma unroll
            for (int ni = 0; ni < 4; ni++) {
                acc[mi][ni] = __builtin_amdgcn_mfma_f32_16x16x32_bf16(ah[mi], bh[ni], acc[mi][ni], 0, 0, 0);
                acc[mi][ni] = __builtin_amdgcn_mfma_f32_16x16x32_bf16(ah[mi], bl[ni], acc[mi][ni], 0, 0, 0);
                acc[mi][ni] = __builtin_amdgcn_mfma_f32_16x16x32_bf16(al[mi], bh[ni], acc[mi][ni], 0, 0, 0);
            }
        __syncthreads();
    }
#pragma unroll
    for (int mi = 0; mi < 4; mi++) {
#pragma unroll
        for (int t = 0; t < 4; t++) {
            int pr = row0 + wrow + mi * 16 + lhi * 4 + t;
#pragma unroll
            for (int ni = 0; ni < 4; ni++) {
                int gc = col0 + wcol + ni * 16 + l15;
                float vv = acc[mi][ni][t];
                if (RESID) vv += resid[(size_t)pr * N + gc];
                C[(size_t)pr * N + gc] = vv;
            }
        }
    }
}

// ---------- fused MoE gate+up (m97-style: global_load_lds staging, BK=32) ----------
__global__ __launch_bounds__(256)
void gemm_gateup_k(const u16* __restrict__ A_g, const u16* __restrict__ Gt,
                   const u16* __restrict__ Ut, u16* __restrict__ act,
                   const int* __restrict__ toklist, const float* __restrict__ gwlist,
                   const int* __restrict__ counts, const int* __restrict__ offsets)
{
    const int e = blockIdx.y;
    const int Meff = counts[e];
    const int nt = blockIdx.x & 31, mt = blockIdx.x >> 5;
    if (mt * BM >= Meff) return;
    const int* tok = toklist + e * Tt;
    const float* gw = gwlist + e * Tt;
    const int rowoff = offsets[e];
    __shared__ __align__(16) u16 As[128 * 32], Gs[128 * 32], Us[128 * 32];  // 24 KB
    const int tid = threadIdx.x, lane = tid & 63, wid = tid >> 6;
    const int wrow = (wid >> 1) * 64, wcol = (wid & 1) * 64;
    const int l15 = lane & 15, lhi = lane >> 4;
    const int row0 = mt * BM, col0 = nt * BN;

    // per-lane staging sources: each 1KB call = 16 rows x 64B; lane -> row=call*16+(l>>2), col=(l&3)*8 elems
    const u16* asrc[2];
#pragma unroll
    for (int j = 0; j < 2; j++) {
        int row = (wid * 2 + j) * 16 + (lane >> 2);
        int pr = row0 + row;
        int tr = (pr < Meff) ? tok[pr] : tok[0];
        asrc[j] = A_g + (size_t)tr * Dd + (lane & 3) * 8;
    }
    const size_t bblk = (size_t)(e * 32 + nt) * (32 * 4096);
    const u16* gsrc = Gt + bblk + (size_t)(wid * 2) * 512 + lane * 8;
    const u16* usrc = Ut + bblk + (size_t)(wid * 2) * 512 + lane * 8;

    f32x4 ag[4][4], au[4][4];
#pragma unroll
    for (int i = 0; i < 4; i++)
#pragma unroll
        for (int j = 0; j < 4; j++) {
            ag[i][j].x = 0.f; ag[i][j].y = 0.f; ag[i][j].z = 0.f; ag[i][j].w = 0.f;
            au[i][j].x = 0.f; au[i][j].y = 0.f; au[i][j].z = 0.f; au[i][j].w = 0.f;
        }
    for (int kt = 0; kt < 32; kt++) {
#pragma unroll
        for (int j = 0; j < 2; j++) {
            glds16(asrc[j] + kt * 32,                    As + (wid * 2 + j) * 512);
            glds16(gsrc + j * 512 + (size_t)kt * 4096,   Gs + (wid * 2 + j) * 512);
            glds16(usrc + j * 512 + (size_t)kt * 4096,   Us + (wid * 2 + j) * 512);
        }
        __syncthreads();   // drains vmcnt -> LDS tiles ready
        bfrag a[4];
#pragma unroll
        for (int mi = 0; mi < 4; mi++)
            a[mi] = *(const bfrag*)&As[(wrow + mi * 16 + l15) * 32 + lhi * 8];
#pragma unroll
        for (int ni = 0; ni < 4; ni++) {
            int rb = (wcol + ni * 16 + l15) * 32 + lhi * 8;
            bfrag bg = *(const bfrag*)&Gs[rb];
            bfrag bu = *(const bfrag*)&Us[rb];
#pragma unroll
            for (int mi = 0; mi < 4; mi++) {
                ag[mi][ni] = __builtin_amdgcn_mfma_f32_16x16x32_bf16(a[mi], bg, ag[mi][ni], 0, 0, 0);
                au[mi][ni] = __builtin_amdgcn_mfma_f32_16x16x32_bf16(a[mi], bu, au[mi][ni], 0, 0, 0);
            }
        }
        __syncthreads();
    }
#pragma unroll
    for (int mi = 0; mi < 4; mi++) {
#pragma unroll
        for (int t = 0; t < 4; t++) {
            int pr = row0 + wrow + mi * 16 + lhi * 4 + t;
            if (pr < Meff) {
                float gwv = gw[pr];
#pragma unroll
                for (int ni = 0; ni < 4; ni++) {
                    int gc = col0 + wcol + ni * 16 + l15;
                    float g = ag[mi][ni][t], u = au[mi][ni][t];
                    float sg = g / (1.0f + expf(-g));
                    act[(size_t)(rowoff + pr) * Fn + gc] = f2bf(sg * u * gwv);
                }
            }
        }
    }
}

// ---------- MoE down (BK=64, XOR-swizzled LDS, glds staging): out[tok] += act @ Wd^T ----------
__global__ __launch_bounds__(256)
void gemm_down_k(const u16* __restrict__ act, const u16* __restrict__ Bt,
                 float* __restrict__ C, const int* __restrict__ toklist,
                 const int* __restrict__ counts, const int* __restrict__ offsets)
{
    const int e = blockIdx.y;
    const int Meff = counts[e];
    const int nt = blockIdx.x & 7, mt = blockIdx.x >> 3;
    if (mt * BM >= Meff) return;
    const int* tok = toklist + e * Tt;
    const int rowoff = offsets[e];
    __shared__ __align__(16) u16 As[128 * 64], Bs[128 * 64];   // 32 KB
    const int tid = threadIdx.x, lane = tid & 63, wid = tid >> 6;
    const int wrow = (wid >> 1) * 64, wcol = (wid & 1) * 64;
    const int l15 = lane & 15, lhi = lane >> 4;
    const int row0 = mt * BM;

    // A staging: 1KB call = 8 rows x 128B; lane -> row=call*8+(l>>3); swizzled source col
    const int xcol = ((lane & 7) ^ (lane >> 3)) << 3;  // elems
    const u16* asrc[4];
#pragma unroll
    for (int c = 0; c < 4; c++) {
        int row = (wid * 4 + c) * 8 + (lane >> 3);
        int pr = row0 + row;
        int rr = (pr < Meff) ? pr : 0;
        asrc[c] = act + (size_t)(rowoff + rr) * Fn + xcol;
    }
    const size_t bblk = (size_t)(e * 8 + nt) * (64 * 8192);
    const u16* bsrc = Bt + bblk + (size_t)(wid * 4) * 512 + lane * 8;

    f32x4 acc[4][4];
#pragma unroll
    for (int i = 0; i < 4; i++)
#pragma unroll
        for (int j = 0; j < 4; j++) { acc[i][j].x = 0.f; acc[i][j].y = 0.f; acc[i][j].z = 0.f; acc[i][j].w = 0.f; }

    for (int kt = 0; kt < 64; kt++) {
#pragma unroll
        for (int c = 0; c < 4; c++) {
            glds16(asrc[c] + kt * 64,                  As + (wid * 4 + c) * 512);
            glds16(bsrc + c * 512 + (size_t)kt * 8192, Bs + (wid * 4 + c) * 512);
        }
        __syncthreads();
#pragma unroll
        for (int kk = 0; kk < 2; kk++) {
            bfrag a[4];
#pragma unroll
            for (int mi = 0; mi < 4; mi++) {
                int row = wrow + mi * 16 + l15;
                int cb = (kk * 64 + lhi * 16) ^ ((row & 7) << 4);
                a[mi] = *(const bfrag*)((const char*)As + row * 128 + cb);
            }
#pragma unroll
            for (int ni = 0; ni < 4; ni++) {
                int row = wcol + ni * 16 + l15;
                int cb = (kk * 64 + lhi * 16) ^ ((row & 7) << 4);
                bfrag b = *(const bfrag*)((const char*)Bs + row * 128 + cb);
#pragma unroll
                for (int mi = 0; mi < 4; mi++)
                    acc[mi][ni] = __builtin_amdgcn_mfma_f32_16x16x32_bf16(a[mi], b, acc[mi][ni], 0, 0, 0);
            }
        }
        __syncthreads();
    }
#pragma unroll
    for (int mi = 0; mi < 4; mi++) {
#pragma unroll
        for (int t = 0; t < 4; t++) {
            int pr = row0 + wrow + mi * 16 + lhi * 4 + t;
            if (pr < Meff) {
                int trow = tok[pr];
#pragma unroll
                for (int ni = 0; ni < 4; ni++) {
                    int gc = nt * BN + wcol + ni * 16 + l15;
                    atomicAdd(&C[(size_t)trow * Dd + gc], acc[mi][ni][t]);
                }
            }
        }
    }
}

// ---------- Flash attention (causal GQA), split-bf16x3 ----------
__global__ __launch_bounds__(256)
void attn_k(const float* __restrict__ qkv, const u16* __restrict__ khi,
            const u16* __restrict__ klo, const u16* __restrict__ vthi,
            const u16* __restrict__ vtlo, u16* __restrict__ chi, u16* __restrict__ clo)
{
    const int qt = (int)gridDim.x - 1 - (int)blockIdx.x;
    const int h = blockIdx.y, b = blockIdx.z;
    const int kvh = h >> 2;
    const int g = b * KVHn + kvh;
    const int tid = threadIdx.x;
    const int lane = tid & 63, wid = tid >> 6;
    const int l15 = lane & 15, lhi = lane >> 4;

    __shared__ __align__(16) u16 Khi[64 * 64];
    __shared__ __align__(16) u16 Klo[64 * 64];
    __shared__ __align__(16) u16 Vhi[64 * 72];
    __shared__ __align__(16) u16 Vlo[64 * 72];
    __shared__ __align__(16) u16 Phi[4 * 16 * 72];
    __shared__ __align__(16) u16 Plo[4 * 16 * 72];

    bfrag qh[2], ql[2];
    {
        const int qrow = qt * 64 + wid * 16 + l15;
        const float* qb = qkv + (size_t)(b * Ss + qrow) * 1536 + h * 64;
#pragma unroll
        for (int ks = 0; ks < 2; ks++) {
            const float* p = qb + ks * 32 + lhi * 8;
            f32x4 u0 = *(const f32x4*)p;
            f32x4 u1 = *(const f32x4*)(p + 4);
            float va[8] = { u0.x * 0.125f, u0.y * 0.125f, u0.z * 0.125f, u0.w * 0.125f,
                            u1.x * 0.125f, u1.y * 0.125f, u1.z * 0.125f, u1.w * 0.125f };
            split8a(va, &qh[ks], &ql[ks]);
        }
    }
    f32x4 O[4];
#pragma unroll
    for (int ni = 0; ni < 4; ni++) { O[ni].x = 0.f; O[ni].y = 0.f; O[ni].z = 0.f; O[ni].w = 0.f; }
    float m_r[4] = { -1e30f, -1e30f, -1e30f, -1e30f };
    float l_r[4] = { 0.f, 0.f, 0.f, 0.f };

    for (int kt = 0; kt <= qt; kt++) {
#pragma unroll
        for (int it = 0; it < 2; it++) {
            int ci = tid + it * 256;
            int kv = ci >> 3, d0 = (ci & 7) << 3;
            size_t ga = (size_t)(b * Ss + kt * 64 + kv) * (KVHn * HDn) + kvh * 64 + d0;
            int boff = kv * 128 + ((d0 * 2) ^ ((kv & 7) << 4));
            *(bfrag*)((char*)Khi + boff) = *(const bfrag*)&khi[ga];
            *(bfrag*)((char*)Klo + boff) = *(const bfrag*)&klo[ga];
        }
#pragma unroll
        for (int it = 0; it < 2; it++) {
            int ci = tid + it * 256;
            int d = ci >> 3, kv0 = (ci & 7) << 3;
            size_t ga = ((size_t)g * 64 + d) * Ss + kt * 64 + kv0;
            *(bfrag*)&Vhi[d * 72 + kv0] = *(const bfrag*)&vthi[ga];
            *(bfrag*)&Vlo[d * 72 + kv0] = *(const bfrag*)&vtlo[ga];
        }
        __syncthreads();
        f32x4 sf[4];
#pragma unroll
        for (int ni = 0; ni < 4; ni++) { sf[ni].x = 0.f; sf[ni].y = 0.f; sf[ni].z = 0.f; sf[ni].w = 0.f; }
#pragma unroll
        for (int ks = 0; ks < 2; ks++) {
#pragma unroll
            for (int ni = 0; ni < 4; ni++) {
                int kv = ni * 16 + l15;
                int dof = ks * 64 + lhi * 16;
                int boff = kv * 128 + (dof ^ ((kv & 7) << 4));
                bfrag kfh = *(const bfrag*)((const char*)Khi + boff);
                bfrag kfl = *(const bfrag*)((const char*)Klo + boff);
                sf[ni] = __builtin_amdgcn_mfma_f32_16x16x32_bf16(qh[ks], kfh, sf[ni], 0, 0, 0);
                sf[ni] = __builtin_amdgcn_mfma_f32_16x16x32_bf16(qh[ks], kfl, sf[ni], 0, 0, 0);
                sf[ni] = __builtin_amdgcn_mfma_f32_16x16x32_bf16(ql[ks], kfh, sf[ni], 0, 0, 0);
            }
        }
        if (kt == qt) {
#pragma unroll
            for (int ni = 0; ni < 4; ni++)
#pragma unroll
                for (int t = 0; t < 4; t++)
                    if (ni * 16 + l15 > wid * 16 + lhi * 4 + t) sf[ni][t] = -1e30f;
        }
        float sfac[4];
#pragma unroll
        for (int t = 0; t < 4; t++) {
            float mx = fmaxf(fmaxf(sf[0][t], sf[1][t]), fmaxf(sf[2][t], sf[3][t]));
#pragma unroll
            for (int o = 1; o < 16; o <<= 1) mx = fmaxf(mx, __shfl_xor(mx, o, 64));
            float mn = fmaxf(m_r[t], mx);
            float sc = expf(m_r[t] - mn);
            m_r[t] = mn;
            float rs = 0.f;
#pragma unroll
            for (int ni = 0; ni < 4; ni++) {
                float p = expf(sf[ni][t] - mn);
                sf[ni][t] = p;
                rs += p;
            }
#pragma unroll
            for (int o = 1; o < 16; o <<= 1) rs += __shfl_xor(rs, o, 64);
            l_r[t] = l_r[t] * sc + rs;
            sfac[t] = sc;
        }
#pragma unroll
        for (int ni = 0; ni < 4; ni++)
#pragma unroll
            for (int t = 0; t < 4; t++) O[ni][t] *= sfac[t];
#pragma unroll
        for (int ni = 0; ni < 4; ni++)
#pragma unroll
            for (int t = 0; t < 4; t++) {
                float p = sf[ni][t];
                u16 hu = f2bf(p);
                int ix = (wid * 16 + lhi * 4 + t) * 72 + ni * 16 + l15;
                Phi[ix] = hu;
                Plo[ix] = f2bf(p - bf2f(hu));
            }
        __syncthreads();
#pragma unroll
        for (int ks = 0; ks < 2; ks++) {
            int pb = (wid * 16 + l15) * 72 + ks * 32 + lhi * 8;
            bfrag pfh = *(const bfrag*)&Phi[pb];
            bfrag pfl = *(const bfrag*)&Plo[pb];
#pragma unroll
            for (int ni = 0; ni < 4; ni++) {
                int vb = (ni * 16 + l15) * 72 + ks * 32 + lhi * 8;
                bfrag vfh = *(const bfrag*)&Vhi[vb];
                bfrag vfl = *(const bfrag*)&Vlo[vb];
                O[ni] = __builtin_amdgcn_mfma_f32_16x16x32_bf16(pfh, vfh, O[ni], 0, 0, 0);
                O[ni] = __builtin_amdgcn_mfma_f32_16x16x32_bf16(pfh, vfl, O[ni], 0, 0, 0);
                O[ni] = __builtin_amdgcn_mfma_f32_16x16x32_bf16(pfl, vfh, O[ni], 0, 0, 0);
            }
        }
        __syncthreads();
    }
#pragma unroll
    for (int t = 0; t < 4; t++) {
        float inv = 1.0f / l_r[t];
        int qrow = qt * 64 + wid * 16 + lhi * 4 + t;
        size_t base = (size_t)(b * Ss + qrow) * Dd + h * 64;
#pragma unroll
        for (int ni = 0; ni < 4; ni++) {
            float val = O[ni][t] * inv;
            u16 hv = f2bf(val);
            chi[base + ni * 16 + l15] = hv;
            clo[base + ni * 16 + l15] = f2bf(val - bf2f(hv));
        }
    }
}

// ---------- Router ----------
__global__ __launch_bounds__(256)
void router_k(const float* __restrict__ h2, const float* __restrict__ rw,
              float* __restrict__ probs, int* __restrict__ counts,
              int* __restrict__ toklist, float* __restrict__ gwlist)
{
    const int t = blockIdx.x;
    const int tid = threadIdx.x;
    const int lane = tid & 63, wid = tid >> 6;
    f32x4 x4 = *(const f32x4*)(h2 + (size_t)t * Dd + tid * 4);
    float part[En];
#pragma unroll
    for (int e = 0; e < En; e++) {
        f32x4 w4 = *(const f32x4*)(rw + (size_t)e * Dd + tid * 4);
        part[e] = x4.x * w4.x + x4.y * w4.y + x4.z * w4.z + x4.w * w4.w;
    }
#pragma unroll
    for (int e = 0; e < En; e++)
#pragma unroll
        for (int o = 1; o < 64; o <<= 1) part[e] += __shfl_xor(part[e], o, 64);
    __shared__ float red[4][En];
    if (lane == 0) {
#pragma unroll
        for (int e = 0; e < En; e++) red[wid][e] = part[e];
    }
    __syncthreads();
    if (tid == 0) {
        float lg[En];
        float mx = -1e30f;
#pragma unroll
        for (int e = 0; e < En; e++) {
            lg[e] = red[0][e] + red[1][e] + red[2][e] + red[3][e];
            mx = fmaxf(mx, lg[e]);
        }
        float pe[En], ssum = 0.f;
#pragma unroll
        for (int e = 0; e < En; e++) { pe[e] = expf(lg[e] - mx); ssum += pe[e]; }
        float inv = 1.0f / ssum;
#pragma unroll
        for (int e = 0; e < En; e++) { pe[e] *= inv; probs[(size_t)t * En + e] = pe[e]; }
        int i0 = 0;
#pragma unroll
        for (int e = 1; e < En; e++) if (pe[e] > pe[i0]) i0 = e;
        int i1 = (i0 == 0) ? 1 : 0;
#pragma unroll
        for (int e = 0; e < En; e++) if (e != i0 && pe[e] > pe[i1]) i1 = e;
        float s2 = pe[i0] + pe[i1];
        int s0 = atomicAdd(&counts[i0], 1);
        toklist[i0 * Tt + s0] = t; gwlist[i0 * Tt + s0] = pe[i0] / s2;
        int s1 = atomicAdd(&counts[i1], 1);
        toklist[i1 * Tt + s1] = t; gwlist[i1 * Tt + s1] = pe[i1] / s2;
    }
}

// ---------- offsets + balance loss ----------
__global__ __launch_bounds__(256)
void finalize_k(const float* __restrict__ probs, const int* __restrict__ counts,
                int* __restrict__ offsets, float* __restrict__ loss_out)
{
    const int tid = threadIdx.x, lane = tid & 63, wid = tid >> 6;
    float ps[En];
#pragma unroll
    for (int e = 0; e < En; e++) ps[e] = 0.f;
    for (int t = tid; t < Tt; t += 256) {
#pragma unroll
        for (int e = 0; e < En; e++) ps[e] += probs[(size_t)t * En + e];
    }
#pragma unroll
    for (int e = 0; e < En; e++)
#pragma unroll
        for (int o = 1; o < 64; o <<= 1) ps[e] += __shfl_xor(ps[e], o, 64);
    __shared__ float red[4][En];
    if (lane == 0) {
#pragma unroll
        for (int e = 0; e < En; e++) red[wid][e] = ps[e];
    }
    __syncthreads();
    if (tid == 0) {
        int o = 0;
        float bl = 0.f;
#pragma unroll
        for (int e = 0; e < En; e++) {
            offsets[e] = o; o += counts[e];
            float pm = (red[0][e] + red[1][e] + red[2][e] + red[3][e]) * (1.0f / Tt);
            float fr = (float)counts[e] * (1.0f / (Tt * 2));
            bl += fr * pm;
        }
        loss_out[0] = 0.01f * (float)En * bl;
    }
}

extern "C" void kernel_launch(void* const* d_in, const int* in_sizes, int n_in,
                              void* d_out, int out_size, void* d_ws, size_t ws_size,
                              hipStream_t stream)
{
    (void)in_sizes; (void)n_in; (void)out_size; (void)ws_size;
    const float* hs  = (const float*)d_in[0];
    const float* ln1 = (const float*)d_in[1];
    const float* wq  = (const float*)d_in[2];
    const float* wk  = (const float*)d_in[3];
    const float* wv  = (const float*)d_in[4];
    const float* wo  = (const float*)d_in[5];
    const float* ln2 = (const float*)d_in[6];
    const float* rw  = (const float*)d_in[7];
    const float* wg  = (const float*)d_in[8];
    const float* wu  = (const float*)d_in[9];
    const float* wd  = (const float*)d_in[10];
    float* out = (float*)d_out;

    char* ws = (char*)d_ws;
    size_t off = 0;
    auto nxt = [&](size_t bytes) { char* p = ws + off; off += (bytes + 255) & ~(size_t)255; return p; };
    // ---- persistent (MoE-era) region ----
    u16* wgt  = (u16*)nxt((size_t)En * Fn * Dd * 2);
    u16* wut  = (u16*)nxt((size_t)En * Fn * Dd * 2);
    u16* wdt  = (u16*)nxt((size_t)En * Dd * Fn * 2);
    float* h2 = (float*)nxt((size_t)Tt * Dd * 4);
    u16* h2b  = (u16*)nxt((size_t)Tt * Dd * 2);
    float* probs = (float*)nxt((size_t)Tt * En * 4);
    int*   tokl  = (int*)nxt((size_t)En * Tt * 4);
    float* gwl   = (float*)nxt((size_t)En * Tt * 4);
    float* ctab  = (float*)nxt((size_t)Ss * 32 * 4);
    float* stab  = (float*)nxt((size_t)Ss * 32 * 4);
    int* counts  = (int*)nxt(256);
    int* offs    = (int*)nxt(256);
    // ---- transient (pre-MoE) region; `act` aliases it ----
    u16* act = (u16*)(ws + off);                     // 8192 x 4096 bf16, aliases below
    float* qkv = (float*)nxt((size_t)Tt * 1536 * 4);
    u16* h1hi = (u16*)nxt((size_t)Tt * Dd * 2);
    u16* h1lo = (u16*)nxt((size_t)Tt * Dd * 2);
    u16* khi  = (u16*)nxt((size_t)Tt * KVHn * HDn * 2);
    u16* klo  = (u16*)nxt((size_t)Tt * KVHn * HDn * 2);
    u16* vthi = (u16*)nxt((size_t)Tt * KVHn * HDn * 2);
    u16* vtlo = (u16*)nxt((size_t)Tt * KVHn * HDn * 2);
    u16* chi  = (u16*)nxt((size_t)Tt * Dd * 2);
    u16* clo  = (u16*)nxt((size_t)Tt * Dd * 2);
    u16* wqkvthi = (u16*)nxt((size_t)1536 * Dd * 2);
    u16* wqkvtlo = (u16*)nxt((size_t)1536 * Dd * 2);
    u16* wothi = (u16*)nxt((size_t)Dd * Dd * 2);
    u16* wotlo = (u16*)nxt((size_t)Dd * Dd * 2);

    rope_tab_k<<<dim3(256), 256, 0, stream>>>(ctab, stab);
    // weight prep
    tconv_k<true ><<<dim3(16 * 16), 256, 0, stream>>>(wq, wqkvthi, wqkvtlo, 1024, 1024,    0, 16);
    tconv_k<true ><<<dim3(16 *  4), 256, 0, stream>>>(wk, wqkvthi, wqkvtlo, 1024,  256, 1024,  4);
    tconv_k<true ><<<dim3(16 *  4), 256, 0, stream>>>(wv, wqkvthi, wqkvtlo, 1024,  256, 1280,  4);
    tconv_k<true ><<<dim3(16 * 16), 256, 0, stream>>>(wo, wothi, wotlo, 1024, 1024, 0, 16);
    tprep_k<32, false><<<dim3(32 * 32, En), 256, 0, stream>>>(wg, wgt, 1024, 4096, 32);
    tprep_k<32, false><<<dim3(32 * 32, En), 256, 0, stream>>>(wu, wut, 1024, 4096, 32);
    tprep_k<64, true ><<<dim3(8 * 64, En), 256, 0, stream>>>(wd, wdt, 4096, 1024, 8);

    rmsnorm_split_k<<<dim3(Tt), 256, 0, stream>>>(hs, ln1, h1hi, h1lo);
    gemm_split_k<false><<<dim3(12 * 32), 256, 0, stream>>>(h1hi, h1lo, wqkvthi, wqkvtlo,
                                                           qkv, nullptr, Tt, 1536, Dd, 12);
    rope_q_k<<<dim3(Tt * Hh * 32 / 256), 256, 0, stream>>>(qkv, ctab, stab);
    kprep_k<<<dim3(Tt * KVHn * 32 / 256), 256, 0, stream>>>(qkv, ctab, stab, khi, klo);
    vprep_k<<<dim3(Ss / 64, Bb * KVHn), 256, 0, stream>>>(qkv, vthi, vtlo);
    attn_k<<<dim3(Ss / 64, Hh, Bb), 256, 0, stream>>>(qkv, khi, klo, vthi, vtlo, chi, clo);
    gemm_split_k<true><<<dim3(8 * 32), 256, 0, stream>>>(chi, clo, wothi, wotlo,
                                                         out, hs, Tt, Dd, Dd, 8);
    rmsnorm2_k<<<dim3(Tt), 256, 0, stream>>>(out, ln2, h2, h2b);
    (void)hipMemsetAsync(counts, 0, 64, stream);
    router_k<<<dim3(Tt), 256, 0, stream>>>(h2, rw, probs, counts, tokl, gwl);
    finalize_k<<<dim3(1), 256, 0, stream>>>(probs, counts, offs, out + (size_t)Tt * Dd);
    gemm_gateup_k<<<dim3(32 * 32, En), 256, 0, stream>>>(h2b, wgt, wut, act, tokl, gwl, counts, offs);
    gemm_down_k<<<dim3(8 * 32, En), 256, 0, stream>>>(act, wdt, out, tokl, counts, offs);
}